// Round 10
// baseline (18050.699 us; speedup 1.0000x reference)
//
#include <hip/hip_runtime.h>

#define NL 4000
#define NC 8000
#define EMB 128
#define ROWC0 4096           // clause region start
#define NRP 12288            // padded total rows (96 panels x 128)
#define NRREAL (ROWC0 + NC)  // 12096 rows with data
#define TSTEPS 30
#define LCHUNK 80
#define NCHUNK 50
#define GBLK 256             // persistent blocks = #CUs (co-residency guaranteed)
#define TBLK 256             // 4 waves/block

typedef __attribute__((ext_vector_type(8))) short bf16x8;
typedef __attribute__((ext_vector_type(4))) float f32x4;

__device__ __forceinline__ short f2bf(float x) {
    union { float f; unsigned u; } v; v.f = x;
    unsigned r = v.u + 0x7fffu + ((v.u >> 16) & 1u);
    return (short)(r >> 16);
}
__device__ __forceinline__ float bf2f(short s) {
    union { unsigned u; float f; } v; v.u = ((unsigned)(unsigned short)s) << 16;
    return v.f;
}
__device__ __forceinline__ float sigf(float x) { return 1.f / (1.f + expf(-x)); }
__device__ __forceinline__ float2 h2f2(unsigned u) {
    union { unsigned v; _Float16 h[2]; } x; x.v = u;
    return make_float2((float)x.h[0], (float)x.h[1]);
}
__device__ __forceinline__ void gload16(const void* g, void* l) {
    __builtin_amdgcn_global_load_lds(
        (const __attribute__((address_space(1))) unsigned int*)g,
        (__attribute__((address_space(3))) unsigned int*)l, 16, 0, 0);
}

struct P {
    short *HAh, *HAl, *HBh, *HBl; float *CA, *CB;
    short *msgsH, *msgsL; _Float16* X;
    short *H1h, *H1l, *H2h, *H2l;
    float* accum; float* out; int* arr; int* rel;
    const float *L_init, *C_init;
    const int *Lp, *Li, *Tp, *Ti;
    const short *W1hL, *W1lL, *W1hC, *W1lC;
    const short *W2hL, *W2lL, *W2hC, *W2lC;
    const short *W3hL, *W3lL, *W3hC, *W3lC;
    const short *WihhL, *WihlL, *WhhhL, *WhhlL;
    const short *WihhC, *WihlC, *WhhhC, *WhhlC;
    const short *V1h, *V1l, *V2h, *V2l;
    const float *b1L, *b1C, *b2L, *b2C, *b3L, *b3C, *LbL, *LbC;
    const float *Vb1, *Vb2, *VW3, *Vb3;
};

// Grid barrier: ONE atomic RMW per block (arrival), then read-only atomic-load
// spin on the release flag (no RMW contention — the R9 lesson). Device scope
// per G16. Co-residency: GBLK=256=#CUs, 64KB LDS, 4 waves -> >=1 block/CU.
__device__ __forceinline__ void gbar(int* arr, int* rel, int epoch) {
    __syncthreads();
    if (threadIdx.x == 0) {
        __threadfence();   // release all prior writes device-wide
        int a = __hip_atomic_fetch_add(arr, 1, __ATOMIC_ACQ_REL, __HIP_MEMORY_SCOPE_AGENT);
        if (a == GBLK - 1) {
            __hip_atomic_store(arr, 0, __ATOMIC_RELAXED, __HIP_MEMORY_SCOPE_AGENT);
            __hip_atomic_store(rel, epoch, __ATOMIC_RELEASE, __HIP_MEMORY_SCOPE_AGENT);
        } else {
            while (__hip_atomic_load(rel, __ATOMIC_ACQUIRE, __HIP_MEMORY_SCOPE_AGENT) != epoch)
                __builtin_amdgcn_s_sleep(1);
        }
        __threadfence();   // acquire: no stale cache reads after barrier
    }
    __syncthreads();
}

// ---------------------------------------------------------------------------
// 128x128 GEMM tile, 4 waves (2x2), double-buffered global_load_lds staging.
// This is R6's verified mfma_gemm inner structure (absmax 0.0) as a device fn.
// OUTM: 1 = split-bf16 out (+relu), 4 = fp16 out, 3 = fused LSTM epilogue.
// ---------------------------------------------------------------------------
template<int KS, int OUTM, bool TWOA, bool RELU>
__device__ void tile128(
    int row0, int c0,
    const short* __restrict__ A1h, const short* __restrict__ A1l,
    const short* __restrict__ A2h, const short* __restrict__ A2l,
    const short* __restrict__ B1hL, const short* __restrict__ B1lL,
    const short* __restrict__ B1hC, const short* __restrict__ B1lC,
    const short* __restrict__ B2hL, const short* __restrict__ B2lL,
    const short* __restrict__ B2hC, const short* __restrict__ B2lC,
    const float* __restrict__ biasL, const float* __restrict__ biasC,
    short* __restrict__ OH, short* __restrict__ OL, float* __restrict__ OF,
    const float* __restrict__ Cold, float* __restrict__ Cnew,
    int Freal, int Fstore,
    short* sAh, short* sAl, short* sBh, short* sBl)
{
    constexpr int KIT = KS / 32;
    constexpr int NIT = (TWOA ? 2 : 1) * KIT;
    const bool isC = (row0 >= ROWC0);
    const int t = threadIdx.x;
    const int lane = t & 63;
    const int w = t >> 6;
    const int wr = w >> 1, wc = w & 1;
    const int l15 = lane & 15;

    __syncthreads();                       // protect LDS reuse across tiles

    f32x4 acc[4][4] = {};

    auto stage = [&](int buf, int it) {
        const int ph = it / KIT;
        const int kc = (it - ph * KIT) * 32;
        const short *Ah, *Al, *Bh, *Bl;
        if (TWOA && ph) {
            Ah = A2h; Al = A2l;
            Bh = isC ? B2hC : B2hL; Bl = isC ? B2lC : B2lL;
        } else {
            Ah = A1h; Al = A1l;
            Bh = isC ? B1hC : B1hL; Bl = isC ? B1lC : B1lL;
        }
#pragma unroll
        for (int q = 0; q < 2; ++q) {      // A: 128 rows x 4 slots / 256 thr
            int c = q * TBLK + t;
            int row = c >> 2, slot = c & 3;
            int gk = kc + ((slot ^ ((row >> 1) & 3)) << 3);
            size_t gi = (size_t)(row0 + row) * KS + gk;
            gload16(Ah + gi, &sAh[buf * 4096 + c * 8]);
            gload16(Al + gi, &sAl[buf * 4096 + c * 8]);
        }
#pragma unroll
        for (int q = 0; q < 2; ++q) {      // B: 128 rows x 4 slots / 256 thr
            int c = q * TBLK + t;
            int row = c >> 2, slot = c & 3;
            int gk = kc + ((slot ^ ((row >> 1) & 3)) << 3);
            size_t gi = (size_t)(c0 + row) * KS + gk;
            gload16(Bh + gi, &sBh[buf * 4096 + c * 8]);
            gload16(Bl + gi, &sBl[buf * 4096 + c * 8]);
        }
    };

    stage(0, 0);
    asm volatile("s_waitcnt vmcnt(0)" ::: "memory");
    __syncthreads();

    int cur = 0;
    for (int it = 0; it < NIT; ++it) {
        if (it + 1 < NIT) stage(cur ^ 1, it + 1);

        bf16x8 af[4][2], bfr[4][2];
#pragma unroll
        for (int s = 0; s < 4; ++s) {
            int row = wr * 64 + s * 16 + l15;
            int slot = (lane >> 4) ^ ((row >> 1) & 3);
            int idx = cur * 4096 + row * 32 + slot * 8;
            af[s][0] = *(const bf16x8*)&sAh[idx];
            af[s][1] = *(const bf16x8*)&sAl[idx];
            int colr = wc * 64 + s * 16 + l15;
            int slotb = (lane >> 4) ^ ((colr >> 1) & 3);
            int idxb = cur * 4096 + colr * 32 + slotb * 8;
            bfr[s][0] = *(const bf16x8*)&sBh[idxb];
            bfr[s][1] = *(const bf16x8*)&sBl[idxb];
        }
#pragma unroll
        for (int s = 0; s < 4; ++s)
#pragma unroll
            for (int u = 0; u < 4; ++u) {
                acc[s][u] = __builtin_amdgcn_mfma_f32_16x16x32_bf16(af[s][0], bfr[u][0], acc[s][u], 0, 0, 0);
                acc[s][u] = __builtin_amdgcn_mfma_f32_16x16x32_bf16(af[s][0], bfr[u][1], acc[s][u], 0, 0, 0);
                acc[s][u] = __builtin_amdgcn_mfma_f32_16x16x32_bf16(af[s][1], bfr[u][0], acc[s][u], 0, 0, 0);
            }

        if (it + 1 < NIT) {
            asm volatile("s_waitcnt vmcnt(0)" ::: "memory");
            __syncthreads();
            cur ^= 1;
        }
    }

    if (OUTM != 3) {
#pragma unroll
        for (int u = 0; u < 4; ++u) {
            int col = c0 + wc * 64 + u * 16 + l15;
            if (col >= Fstore) continue;
            float bv = (col < Freal) ? (isC ? biasC[col] : biasL[col]) : 0.f;
#pragma unroll
            for (int s = 0; s < 4; ++s)
#pragma unroll
                for (int j = 0; j < 4; ++j) {
                    int row = row0 + wr * 64 + s * 16 + (lane >> 4) * 4 + j;
                    float v = acc[s][u][j] + bv;
                    if (RELU) v = fmaxf(v, 0.f);
                    size_t oi = (size_t)row * Fstore + col;
                    if (OUTM == 1) {
                        short h = f2bf(v);
                        OH[oi] = h;
                        OL[oi] = f2bf(v - bf2f(h));
                    } else {
                        ((_Float16*)OF)[oi] = (_Float16)v;
                    }
                }
        }
    } else {
        const int q = lane & 3;
#pragma unroll
        for (int u = 0; u < 4; ++u) {
            int colp = c0 + wc * 64 + u * 16 + l15;
            int wrr = (colp & 3) * 128 + (colp >> 2);
            float bv = isC ? biasC[wrr] : biasL[wrr];
            int j = colp >> 2;
#pragma unroll
            for (int s = 0; s < 4; ++s) {
                float ii = 0.f, ff = 0.f, gg = 0.f, oo = 0.f;
#pragma unroll
                for (int r2 = 0; r2 < 4; ++r2) {
                    float v0 = acc[s][u][r2] + bv;
                    float x1 = __shfl_xor(v0, 1);
                    float x2 = __shfl_xor(v0, 2);
                    float x3 = __shfl_xor(v0, 3);
                    float iv = (q == 0) ? v0 : (q == 1) ? x1 : (q == 2) ? x2 : x3;
                    float fv = (q == 0) ? x1 : (q == 1) ? v0 : (q == 2) ? x3 : x2;
                    float gv = (q == 0) ? x2 : (q == 1) ? x3 : (q == 2) ? v0 : x1;
                    float ov = (q == 0) ? x3 : (q == 1) ? x2 : (q == 2) ? x1 : v0;
                    if (q == r2) { ii = iv; ff = fv; gg = gv; oo = ov; }
                }
                int row = row0 + wr * 64 + s * 16 + (lane >> 4) * 4 + q;
                size_t ci = (size_t)row * 128 + j;
                float c2 = sigf(ff) * Cold[ci] + sigf(ii) * tanhf(gg);
                float h2 = sigf(oo) * tanhf(c2);
                Cnew[ci] = c2;
                short h = f2bf(h2);
                OH[ci] = h;
                OL[ci] = f2bf(h2 - bf2f(h));
            }
        }
    }
}

// One row per wave (R7-verbatim arithmetic), fp16 X in, split-bf16 msgs out.
__device__ void spmm_row(int r, const P& p)
{
    const int cp = (threadIdx.x & 63) * 2;
    const _Float16* X = p.X;
    float s0 = 0.f, s1 = 0.f;
    if (r < NL) {
        int b = p.Lp[r], e = p.Lp[r + 1];
        int i = b;
        for (; i + 3 < e; i += 4) {
            unsigned u0 = *(const unsigned*)&X[(size_t)(ROWC0 + p.Li[i]) * EMB + cp];
            unsigned u1 = *(const unsigned*)&X[(size_t)(ROWC0 + p.Li[i + 1]) * EMB + cp];
            unsigned u2 = *(const unsigned*)&X[(size_t)(ROWC0 + p.Li[i + 2]) * EMB + cp];
            unsigned u3 = *(const unsigned*)&X[(size_t)(ROWC0 + p.Li[i + 3]) * EMB + cp];
            float2 v0 = h2f2(u0), v1 = h2f2(u1), v2 = h2f2(u2), v3 = h2f2(u3);
            s0 += v0.x + v1.x + v2.x + v3.x;
            s1 += v0.y + v1.y + v2.y + v3.y;
        }
        for (; i < e; ++i) {
            float2 v = h2f2(*(const unsigned*)&X[(size_t)(ROWC0 + p.Li[i]) * EMB + cp]);
            s0 += v.x; s1 += v.y;
        }
    } else if (r >= ROWC0 && r < NRREAL) {
        int c = r - ROWC0;
        int b = p.Tp[c], e = p.Tp[c + 1];
        int i = b;
        for (; i + 3 < e; i += 4) {
            unsigned u0 = *(const unsigned*)&X[(size_t)p.Ti[i] * EMB + cp];
            unsigned u1 = *(const unsigned*)&X[(size_t)p.Ti[i + 1] * EMB + cp];
            unsigned u2 = *(const unsigned*)&X[(size_t)p.Ti[i + 2] * EMB + cp];
            unsigned u3 = *(const unsigned*)&X[(size_t)p.Ti[i + 3] * EMB + cp];
            float2 v0 = h2f2(u0), v1 = h2f2(u1), v2 = h2f2(u2), v3 = h2f2(u3);
            s0 += v0.x + v1.x + v2.x + v3.x;
            s1 += v0.y + v1.y + v2.y + v3.y;
        }
        for (; i < e; ++i) {
            float2 v = h2f2(*(const unsigned*)&X[(size_t)p.Ti[i] * EMB + cp]);
            s0 += v.x; s1 += v.y;
        }
    } else {
        return;   // pad row: msgs stays zero (init)
    }
    size_t oi = (size_t)r * EMB + cp;
    short h0 = f2bf(s0), h1 = f2bf(s1);
    *(unsigned*)&p.msgsH[oi] = (unsigned)(unsigned short)h0 | ((unsigned)(unsigned short)h1 << 16);
    short l0 = f2bf(s0 - bf2f(h0)), l1 = f2bf(s1 - bf2f(h1));
    *(unsigned*)&p.msgsL[oi] = (unsigned)(unsigned short)l0 | ((unsigned)(unsigned short)l1 << 16);
}

// ---------------------------------------------------------------------------
// Persistent mega-kernel: tile-parallel grid-strided phases + light barriers.
// ---------------------------------------------------------------------------
__global__ __launch_bounds__(TBLK) void mega(P p)
{
    __shared__ short sAh[2 * 4096];
    __shared__ short sAl[2 * 4096];
    __shared__ short sBh[2 * 4096];
    __shared__ short sBl[2 * 4096];
    const int t = threadIdx.x;
    const size_t NE = (size_t)NRP * EMB;
    int ep = 0;

    // init (grid-strided)
    for (size_t idx = (size_t)blockIdx.x * TBLK + t; idx < NE; idx += (size_t)GBLK * TBLK) {
        int r = (int)(idx >> 7);
        int e = (int)(idx & 127);
        float h = 0.f;
        if (r < NL) h = p.L_init[e];
        else if (r >= ROWC0 && r < NRREAL) h = p.C_init[e];
        short hh = f2bf(h);
        p.HAh[idx] = hh;
        p.HAl[idx] = f2bf(h - bf2f(hh));
        p.CA[idx] = 0.f;
        if (r >= NRREAL || (r >= NL && r < ROWC0)) { p.msgsH[idx] = 0; p.msgsL[idx] = 0; }
    }
    if (blockIdx.x == 0 && t == 0) p.accum[0] = 0.f;
    gbar(p.arr, p.rel, ++ep);

    for (int step = 0; step < TSTEPS; ++step) {
        const short* Hch = (step & 1) ? p.HBh : p.HAh;
        const short* Hcl = (step & 1) ? p.HBl : p.HAl;
        short* Hnh = (step & 1) ? p.HAh : p.HBh;
        short* Hnl = (step & 1) ? p.HAl : p.HBl;
        const float* Ccur = (step & 1) ? p.CB : p.CA;
        float* Cnxt = (step & 1) ? p.CA : p.CB;

        // G1: H -> H1 (relu): 96 panels x 4 col-tiles = 384 tiles
#pragma unroll 1
        for (int tile = blockIdx.x; tile < 384; tile += GBLK)
            tile128<128, 1, false, true>((tile >> 2) * 128, (tile & 3) * 128,
                Hch, Hcl, nullptr, nullptr,
                p.W1hL, p.W1lL, p.W1hC, p.W1lC, nullptr, nullptr, nullptr, nullptr,
                p.b1L, p.b1C, p.H1h, p.H1l, nullptr, nullptr, nullptr,
                400, 416, sAh, sAl, sBh, sBl);
        gbar(p.arr, p.rel, ++ep);

        // G2: H1 -> H2 (relu): 96 x 2 = 192 tiles
#pragma unroll 1
        for (int tile = blockIdx.x; tile < 192; tile += GBLK)
            tile128<416, 1, false, true>((tile >> 1) * 128, (tile & 1) * 128,
                p.H1h, p.H1l, nullptr, nullptr,
                p.W2hL, p.W2lL, p.W2hC, p.W2lC, nullptr, nullptr, nullptr, nullptr,
                p.b2L, p.b2C, p.H2h, p.H2l, nullptr, nullptr, nullptr,
                200, 224, sAh, sAl, sBh, sBl);
        gbar(p.arr, p.rel, ++ep);

        // G3: H2 -> X (fp16): 96 tiles
#pragma unroll 1
        for (int tile = blockIdx.x; tile < 96; tile += GBLK)
            tile128<224, 4, false, false>(tile * 128, 0,
                p.H2h, p.H2l, nullptr, nullptr,
                p.W3hL, p.W3lL, p.W3hC, p.W3lC, nullptr, nullptr, nullptr, nullptr,
                p.b3L, p.b3C, nullptr, nullptr, (float*)p.X, nullptr, nullptr,
                128, 128, sAh, sAl, sBh, sBl);
        gbar(p.arr, p.rel, ++ep);

        // SpMM: one row per wave, grid-strided over all waves
#pragma unroll 1
        for (int r = blockIdx.x * 4 + (t >> 6); r < NRREAL; r += GBLK * 4)
            spmm_row(r, p);
        gbar(p.arr, p.rel, ++ep);

        // G4: gates + fused LSTM: 96 x 4 = 384 tiles
#pragma unroll 1
        for (int tile = blockIdx.x; tile < 384; tile += GBLK)
            tile128<128, 3, true, false>((tile >> 2) * 128, (tile & 3) * 128,
                p.msgsH, p.msgsL, Hch, Hcl,
                p.WihhL, p.WihlL, p.WihhC, p.WihlC,
                p.WhhhL, p.WhhlL, p.WhhhC, p.WhhlC,
                p.LbL, p.LbC, Hnh, Hnl, nullptr, Ccur, Cnxt,
                512, 512, sAh, sAl, sBh, sBl);
        gbar(p.arr, p.rel, ++ep);
    }

    // vote MLP on lit rows (final H in HA after 30 steps): 32 panels
#pragma unroll 1
    for (int tile = blockIdx.x; tile < 128; tile += GBLK)
        tile128<128, 1, false, true>((tile >> 2) * 128, (tile & 3) * 128,
            p.HAh, p.HAl, nullptr, nullptr,
            p.V1h, p.V1l, p.V1h, p.V1l, nullptr, nullptr, nullptr, nullptr,
            p.Vb1, p.Vb1, p.H1h, p.H1l, nullptr, nullptr, nullptr,
            400, 416, sAh, sAl, sBh, sBl);
    gbar(p.arr, p.rel, ++ep);
#pragma unroll 1
    for (int tile = blockIdx.x; tile < 64; tile += GBLK)
        tile128<416, 1, false, true>((tile >> 1) * 128, (tile & 1) * 128,
            p.H1h, p.H1l, nullptr, nullptr,
            p.V2h, p.V2l, p.V2h, p.V2l, nullptr, nullptr, nullptr, nullptr,
            p.Vb2, p.Vb2, p.H2h, p.H2l, nullptr, nullptr, nullptr,
            200, 224, sAh, sAl, sBh, sBl);
    gbar(p.arr, p.rel, ++ep);
    // vote reduce: one row per wave
#pragma unroll 1
    for (int r = blockIdx.x * 4 + (t >> 6); r < NL; r += GBLK * 4) {
        int lane = t & 63;
        float s = 0.f;
        const short* xh = &p.H2h[(size_t)r * 224];
        const short* xl = &p.H2l[(size_t)r * 224];
        for (int k = lane; k < 200; k += 64) s += (bf2f(xh[k]) + bf2f(xl[k])) * p.VW3[k];
#pragma unroll
        for (int o = 32; o > 0; o >>= 1) s += __shfl_down(s, o);
        if (lane == 0) {
            float v = 1.f / (1.f + expf(-(s + p.Vb3[0])));
            atomicAdd(p.accum, v);
        }
    }
    gbar(p.arr, p.rel, ++ep);
    if (blockIdx.x == 0 && t == 0) {
        float avg = p.accum[0] / (float)NL;
        p.out[0] = logf(avg / (1.f - avg));
    }
}

__global__ void reset_k(int* arr, int* rel, float* accum)
{
    arr[0] = 0;
    rel[0] = 0;
    accum[0] = 0.f;
}

struct SplitJobs {
    const float* src[12];
    short* dh[12]; short* dl[12];
    int rows[12], cols[12], prows[12], pcols[12], perm[12];
};

__global__ __launch_bounds__(256) void split_all(SplitJobs J)
{
    int j = blockIdx.y;
    int i = blockIdx.x * 256 + threadIdx.x;
    int pr = J.prows[j], pc = J.pcols[j];
    if (i >= pr * pc) return;
    int pp = i / pc, c = i - pp * pc;
    int r = J.perm[j] ? (((pp & 3) << 7) | (pp >> 2)) : pp;
    float v = (r < J.rows[j] && c < J.cols[j]) ? J.src[j][(size_t)r * J.cols[j] + c] : 0.f;
    short h = f2bf(v);
    J.dh[j][i] = h;
    J.dl[j][i] = f2bf(v - bf2f(h));
}

__global__ __launch_bounds__(256) void count_rows_L(const float* __restrict__ M, int* __restrict__ cnt)
{
    int l = blockIdx.x, t = threadIdx.x;
    int c_ = 0;
    for (int c = t; c < NC; c += 256) c_ += (M[(size_t)l * NC + c] != 0.f) ? 1 : 0;
#pragma unroll
    for (int off = 32; off > 0; off >>= 1) c_ += __shfl_down(c_, off);
    __shared__ int w[4];
    if ((t & 63) == 0) w[t >> 6] = c_;
    __syncthreads();
    if (t == 0) cnt[l] = w[0] + w[1] + w[2] + w[3];
}

__global__ __launch_bounds__(256) void scan_excl(const int* __restrict__ in, int* __restrict__ out, int n)
{
    const int t = threadIdx.x;
    const int per = (n + 255) >> 8;
    __shared__ int part[256];
    int s = 0;
    const int start = t * per;
    for (int i = 0; i < per; ++i) { int idx = start + i; if (idx < n) s += in[idx]; }
    part[t] = s;
    __syncthreads();
    for (int off = 1; off < 256; off <<= 1) {
        int v = (t >= off) ? part[t - off] : 0;
        __syncthreads();
        part[t] += v;
        __syncthreads();
    }
    int run = (t == 0) ? 0 : part[t - 1];
    for (int i = 0; i < per; ++i) {
        int idx = start + i;
        if (idx < n) { out[idx] = run; run += in[idx]; }
    }
    if (t == 255) out[n] = part[255];
}

__global__ __launch_bounds__(256) void fill_L(const float* __restrict__ M,
                                              const int* __restrict__ Lp, int* __restrict__ Lidx)
{
    int l = blockIdx.x, t = threadIdx.x, lane = t & 63, wid = t >> 6;
    __shared__ int wcnt[4];
    __shared__ int base;
    if (t == 0) base = Lp[l];
    __syncthreads();
    for (int c0 = 0; c0 < NC; c0 += 256) {
        int c = c0 + t;
        bool pr = (c < NC) && (M[(size_t)l * NC + c] != 0.f);
        unsigned long long m = __ballot(pr);
        if (lane == 0) wcnt[wid] = (int)__popcll(m);
        __syncthreads();
        int off = base;
        for (int w = 0; w < wid; ++w) off += wcnt[w];
        int rank = (int)__popcll(m & ((1ull << lane) - 1ull));
        if (pr) Lidx[off + rank] = c;
        __syncthreads();
        if (t == 0) base += wcnt[0] + wcnt[1] + wcnt[2] + wcnt[3];
        __syncthreads();
    }
}

__global__ __launch_bounds__(256) void count_T(const float* __restrict__ M, int* __restrict__ cnt2d)
{
    int s = blockIdx.y;
    int c = blockIdx.x * 256 + threadIdx.x;
    if (c >= NC) return;
    int n = 0;
    int l0 = s * LCHUNK, l1 = l0 + LCHUNK;
    for (int l = l0; l < l1; ++l) n += (M[(size_t)l * NC + c] != 0.f) ? 1 : 0;
    cnt2d[(size_t)s * NC + c] = n;
}

__global__ __launch_bounds__(256) void colscan_T(const int* __restrict__ cnt2d,
                                                 int* __restrict__ cum2d, int* __restrict__ cntT)
{
    int c = blockIdx.x * 256 + threadIdx.x;
    if (c >= NC) return;
    int run = 0;
    for (int s = 0; s < NCHUNK; ++s) {
        cum2d[(size_t)s * NC + c] = run;
        run += cnt2d[(size_t)s * NC + c];
    }
    cntT[c] = run;
}

__global__ __launch_bounds__(256) void fill_T(const float* __restrict__ M,
                                              const int* __restrict__ Tp, const int* __restrict__ cum2d,
                                              int* __restrict__ Tidx)
{
    int s = blockIdx.y;
    int c = blockIdx.x * 256 + threadIdx.x;
    if (c >= NC) return;
    int pos = Tp[c] + cum2d[(size_t)s * NC + c];
    int l0 = s * LCHUNK, l1 = l0 + LCHUNK;
    for (int l = l0; l < l1; ++l) {
        if (M[(size_t)l * NC + c] != 0.f) Tidx[pos++] = l;
    }
}

extern "C" void kernel_launch(void* const* d_in, const int* in_sizes, int n_in,
                              void* d_out, int out_size, void* d_ws, size_t ws_size,
                              hipStream_t stream)
{
    const float* M      = (const float*)d_in[0];
    const float* L_init = (const float*)d_in[1];
    const float* C_init = (const float*)d_in[2];
    const float* LC_W1 = (const float*)d_in[3];  const float* LC_b1 = (const float*)d_in[4];
    const float* LC_W2 = (const float*)d_in[5];  const float* LC_b2 = (const float*)d_in[6];
    const float* LC_W3 = (const float*)d_in[7];  const float* LC_b3 = (const float*)d_in[8];
    const float* CL_W1 = (const float*)d_in[9];  const float* CL_b1 = (const float*)d_in[10];
    const float* CL_W2 = (const float*)d_in[11]; const float* CL_b2 = (const float*)d_in[12];
    const float* CL_W3 = (const float*)d_in[13]; const float* CL_b3 = (const float*)d_in[14];
    const float* L_Wih = (const float*)d_in[15]; const float* L_Whh = (const float*)d_in[16];
    const float* L_b   = (const float*)d_in[17];
    const float* C_Wih = (const float*)d_in[18]; const float* C_Whh = (const float*)d_in[19];
    const float* C_b   = (const float*)d_in[20];
    const float* V_W1 = (const float*)d_in[21]; const float* V_b1 = (const float*)d_in[22];
    const float* V_W2 = (const float*)d_in[23]; const float* V_b2 = (const float*)d_in[24];
    const float* V_W3 = (const float*)d_in[25]; const float* V_b3 = (const float*)d_in[26];

    char* ws = (char*)d_ws;
    size_t off = 0;
    auto alloc = [&](size_t bytes) -> void* {
        void* pt = ws + off;
        off += (bytes + 255) & ~(size_t)255;
        return pt;
    };
    const size_t NE = (size_t)NRP * EMB;
    P p{};
    p.HAh = (short*)alloc(NE * 2); p.HAl = (short*)alloc(NE * 2);
    p.HBh = (short*)alloc(NE * 2); p.HBl = (short*)alloc(NE * 2);
    p.CA = (float*)alloc(NE * 4);  p.CB = (float*)alloc(NE * 4);
    p.msgsH = (short*)alloc(NE * 2); p.msgsL = (short*)alloc(NE * 2);
    p.X = (_Float16*)alloc(NE * 2);
    p.H1h = (short*)alloc((size_t)NRP * 416 * 2); p.H1l = (short*)alloc((size_t)NRP * 416 * 2);
    p.H2h = (short*)alloc((size_t)NRP * 224 * 2); p.H2l = (short*)alloc((size_t)NRP * 224 * 2);
    p.accum = (float*)alloc(256);
    p.arr = (int*)alloc(256);
    p.rel = (int*)alloc(256);
    short* W1hL = (short*)alloc(512 * 128 * 2); short* W1lL = (short*)alloc(512 * 128 * 2);
    short* W1hC = (short*)alloc(512 * 128 * 2); short* W1lC = (short*)alloc(512 * 128 * 2);
    short* W2hL = (short*)alloc(256 * 416 * 2); short* W2lL = (short*)alloc(256 * 416 * 2);
    short* W2hC = (short*)alloc(256 * 416 * 2); short* W2lC = (short*)alloc(256 * 416 * 2);
    short* W3hL = (short*)alloc(128 * 224 * 2); short* W3lL = (short*)alloc(128 * 224 * 2);
    short* W3hC = (short*)alloc(128 * 224 * 2); short* W3lC = (short*)alloc(128 * 224 * 2);
    short* WihhL = (short*)alloc(512 * 128 * 2); short* WihlL = (short*)alloc(512 * 128 * 2);
    short* WhhhL = (short*)alloc(512 * 128 * 2); short* WhhlL = (short*)alloc(512 * 128 * 2);
    short* WihhC = (short*)alloc(512 * 128 * 2); short* WihlC = (short*)alloc(512 * 128 * 2);
    short* WhhhC = (short*)alloc(512 * 128 * 2); short* WhhlC = (short*)alloc(512 * 128 * 2);
    short* V1h = (short*)alloc(512 * 128 * 2); short* V1l = (short*)alloc(512 * 128 * 2);
    short* V2h = (short*)alloc(256 * 416 * 2); short* V2l = (short*)alloc(256 * 416 * 2);
    int* Lp   = (int*)alloc(4104 * 4);
    int* Tp   = (int*)alloc(8104 * 4);
    int* Lidx = (int*)alloc(1000000 * 4);
    int* Tidx = (int*)alloc(1000000 * 4);
    int* cnt2d = (int*)alloc((size_t)NCHUNK * NC * 4);
    int* cum2d = (int*)alloc((size_t)NCHUNK * NC * 4);
    int* cntL = (int*)alloc(4096 * 4);
    int* cntT = (int*)alloc(8192 * 4);
    (void)ws_size; (void)in_sizes; (void)n_in; (void)out_size;

    p.W1hL = W1hL; p.W1lL = W1lL; p.W1hC = W1hC; p.W1lC = W1lC;
    p.W2hL = W2hL; p.W2lL = W2lL; p.W2hC = W2hC; p.W2lC = W2lC;
    p.W3hL = W3hL; p.W3lL = W3lL; p.W3hC = W3hC; p.W3lC = W3lC;
    p.WihhL = WihhL; p.WihlL = WihlL; p.WhhhL = WhhhL; p.WhhlL = WhhlL;
    p.WihhC = WihhC; p.WihlC = WihlC; p.WhhhC = WhhhC; p.WhhlC = WhhlC;
    p.V1h = V1h; p.V1l = V1l; p.V2h = V2h; p.V2l = V2l;
    p.b1L = LC_b1; p.b1C = CL_b1; p.b2L = LC_b2; p.b2C = CL_b2;
    p.b3L = LC_b3; p.b3C = CL_b3; p.LbL = L_b; p.LbC = C_b;
    p.Vb1 = V_b1; p.Vb2 = V_b2; p.VW3 = V_W3; p.Vb3 = V_b3;
    p.L_init = L_init; p.C_init = C_init;
    p.Lp = Lp; p.Li = Lidx; p.Tp = Tp; p.Ti = Tidx;
    p.out = (float*)d_out;

    // CSR build
    count_rows_L<<<NL, 256, 0, stream>>>(M, cntL);
    scan_excl<<<1, 256, 0, stream>>>(cntL, Lp, NL);
    fill_L<<<NL, 256, 0, stream>>>(M, Lp, Lidx);
    {
        dim3 g((NC + 255) / 256, NCHUNK);
        count_T<<<g, 256, 0, stream>>>(M, cnt2d);
        colscan_T<<<(NC + 255) / 256, 256, 0, stream>>>(cnt2d, cum2d, cntT);
        scan_excl<<<1, 256, 0, stream>>>(cntT, Tp, NC);
        fill_T<<<g, 256, 0, stream>>>(M, Tp, cum2d, Tidx);
    }

    // merged weight split (1 dispatch)
    SplitJobs Jb{};
    auto setj = [&](int j, const float* s, short* dh, short* dl, int r, int c, int pr, int pc, int pm) {
        Jb.src[j] = s; Jb.dh[j] = dh; Jb.dl[j] = dl;
        Jb.rows[j] = r; Jb.cols[j] = c; Jb.prows[j] = pr; Jb.pcols[j] = pc; Jb.perm[j] = pm;
    };
    setj(0, LC_W1, W1hL, W1lL, 400, 128, 512, 128, 0);
    setj(1, CL_W1, W1hC, W1lC, 400, 128, 512, 128, 0);
    setj(2, LC_W2, W2hL, W2lL, 200, 400, 256, 416, 0);
    setj(3, CL_W2, W2hC, W2lC, 200, 400, 256, 416, 0);
    setj(4, LC_W3, W3hL, W3lL, 128, 200, 128, 224, 0);
    setj(5, CL_W3, W3hC, W3lC, 128, 200, 128, 224, 0);
    setj(6, L_Wih, WihhL, WihlL, 512, 128, 512, 128, 1);
    setj(7, L_Whh, WhhhL, WhhlL, 512, 128, 512, 128, 1);
    setj(8, C_Wih, WihhC, WihlC, 512, 128, 512, 128, 1);
    setj(9, C_Whh, WhhhC, WhhlC, 512, 128, 512, 128, 1);
    setj(10, V_W1, V1h, V1l, 400, 128, 512, 128, 0);
    setj(11, V_W2, V2h, V2l, 200, 400, 256, 416, 0);
    {
        dim3 g((106496 + 255) / 256, 12);
        split_all<<<g, 256, 0, stream>>>(Jb);
    }

    // barrier/accum reset, then the persistent mega-kernel (normal launch)
    reset_k<<<1, 1, 0, stream>>>(p.arr, p.rel, p.accum);
    mega<<<GBLK, TBLK, 0, stream>>>(p);
}

// Round 11
// 3564.568 us; speedup vs baseline: 5.0639x; 5.0639x over previous
//
#include <hip/hip_runtime.h>

#define NL 4000
#define NC 8000
#define EMB 128
#define ROWC0 4096           // clause region start (64-aligned)
#define NRP 12288            // padded total rows (192 x 64)
#define NRREAL (ROWC0 + NC)  // 12096 rows with data
#define TSTEPS 30
#define LCHUNK 80
#define NCHUNK 50

typedef __attribute__((ext_vector_type(8))) short bf16x8;
typedef __attribute__((ext_vector_type(4))) float f32x4;

__device__ __forceinline__ short f2bf(float x) {
    union { float f; unsigned u; } v; v.f = x;
    unsigned r = v.u + 0x7fffu + ((v.u >> 16) & 1u);
    return (short)(r >> 16);
}
__device__ __forceinline__ float bf2f(short s) {
    union { unsigned u; float f; } v; v.u = ((unsigned)(unsigned short)s) << 16;
    return v.f;
}
__device__ __forceinline__ float sigf(float x) { return 1.f / (1.f + expf(-x)); }
__device__ __forceinline__ float2 h2f2(unsigned u) {
    union { unsigned v; _Float16 h[2]; } x; x.v = u;
    return make_float2((float)x.h[0], (float)x.h[1]);
}
__device__ __forceinline__ void gload16(const void* g, void* l) {
    __builtin_amdgcn_global_load_lds(
        (const __attribute__((address_space(1))) unsigned int*)g,
        (__attribute__((address_space(3))) unsigned int*)l, 16, 0, 0);
}

// ---------------------------------------------------------------------------
// Split-bf16 MFMA GEMM, 64x64 tile, 256 thr (4 waves 2x2, wave-tile 32x32).
// SINGLE-buffer 128-K mega-chunk staging: one async burst + one drain per
// 128-K (vs 4 barrier rounds before). 64 KB LDS -> 2 blocks/CU so one
// block's staging overlaps the other's MFMA run.
// product = Ah*Wh + Ah*Wl + Al*Wh in fp32 acc (R2-R7 verified numerics).
// OUTM: 1 = split-bf16 out (+relu), 4 = fp16 out, 3 = fused LSTM epilogue
// (gate-permuted weights; R5-R7 verified). Rows < ROWC0 use L set, else C.
// ---------------------------------------------------------------------------
template<int KS, int OUTM, bool TWOA, bool RELU>
__global__ __launch_bounds__(256) void gemm64(
    const short* __restrict__ A1h, const short* __restrict__ A1l,
    const short* __restrict__ A2h, const short* __restrict__ A2l,
    const short* __restrict__ B1hL, const short* __restrict__ B1lL,
    const short* __restrict__ B1hC, const short* __restrict__ B1lC,
    const short* __restrict__ B2hL, const short* __restrict__ B2lL,
    const short* __restrict__ B2hC, const short* __restrict__ B2lC,
    const float* __restrict__ biasL, const float* __restrict__ biasC,
    short* __restrict__ OH, short* __restrict__ OL, float* __restrict__ OF,
    const float* __restrict__ Cold, float* __restrict__ Cnew,
    int Freal, int Fstore)
{
    __shared__ short sAh[4 * 2048];   // [chunk32 q][row 64][32] per split
    __shared__ short sAl[4 * 2048];
    __shared__ short sBh[4 * 2048];
    __shared__ short sBl[4 * 2048];

    const int row0 = blockIdx.y * 64;
    const int c0 = blockIdx.x * 64;
    const bool isC = (row0 >= ROWC0);
    const int t = threadIdx.x;
    const int lane = t & 63;
    const int w = t >> 6;
    const int wr = w >> 1, wc = w & 1;
    const int l15 = lane & 15;

    f32x4 acc[2][2] = {};
    bool first = true;

    const int nph = TWOA ? 2 : 1;
    for (int ph = 0; ph < nph; ++ph) {
        const short* Ah = (TWOA && ph) ? A2h : A1h;
        const short* Al = (TWOA && ph) ? A2l : A1l;
        const short* Bh = (TWOA && ph) ? (isC ? B2hC : B2hL) : (isC ? B1hC : B1hL);
        const short* Bl = (TWOA && ph) ? (isC ? B2lC : B2lL) : (isC ? B1lC : B1lL);

        for (int kc0 = 0; kc0 < KS; kc0 += 128) {
            const int n32 = ((KS - kc0) >> 5) < 4 ? ((KS - kc0) >> 5) : 4;
            if (!first) __syncthreads();   // buffer free (prev chunk consumed)
            first = false;
            // ---- stage whole chunk: per q, each thread 1 unit of A + B (x2 splits)
            const int row = t >> 2, slot = t & 3;
#pragma unroll 4
            for (int q = 0; q < n32; ++q) {
                int gk = kc0 + q * 32 + ((slot ^ ((row >> 1) & 3)) << 3);
                size_t ga = (size_t)(row0 + row) * KS + gk;
                size_t gb = (size_t)(c0 + row) * KS + gk;
                gload16(Ah + ga, &sAh[q * 2048 + t * 8]);
                gload16(Al + ga, &sAl[q * 2048 + t * 8]);
                gload16(Bh + gb, &sBh[q * 2048 + t * 8]);
                gload16(Bl + gb, &sBl[q * 2048 + t * 8]);
            }
            asm volatile("s_waitcnt vmcnt(0)" ::: "memory");
            __syncthreads();
            // ---- compute whole chunk
#pragma unroll 4
            for (int q = 0; q < n32; ++q) {
                bf16x8 af[2][2], bf[2][2];
#pragma unroll
                for (int s = 0; s < 2; ++s) {
                    int ar = wr * 32 + s * 16 + l15;
                    int aslot = (lane >> 4) ^ ((ar >> 1) & 3);
                    int ai = q * 2048 + ar * 32 + aslot * 8;
                    af[s][0] = *(const bf16x8*)&sAh[ai];
                    af[s][1] = *(const bf16x8*)&sAl[ai];
                    int br = wc * 32 + s * 16 + l15;
                    int bslot = (lane >> 4) ^ ((br >> 1) & 3);
                    int bi = q * 2048 + br * 32 + bslot * 8;
                    bf[s][0] = *(const bf16x8*)&sBh[bi];
                    bf[s][1] = *(const bf16x8*)&sBl[bi];
                }
#pragma unroll
                for (int s = 0; s < 2; ++s)
#pragma unroll
                    for (int u = 0; u < 2; ++u) {
                        acc[s][u] = __builtin_amdgcn_mfma_f32_16x16x32_bf16(af[s][0], bf[u][0], acc[s][u], 0, 0, 0);
                        acc[s][u] = __builtin_amdgcn_mfma_f32_16x16x32_bf16(af[s][0], bf[u][1], acc[s][u], 0, 0, 0);
                        acc[s][u] = __builtin_amdgcn_mfma_f32_16x16x32_bf16(af[s][1], bf[u][0], acc[s][u], 0, 0, 0);
                    }
            }
        }
    }

    if (OUTM != 3) {
        // C/D frag layout: col = lane&15, row = (lane>>4)*4 + reg (m89)
#pragma unroll
        for (int u = 0; u < 2; ++u) {
            int col = c0 + wc * 32 + u * 16 + l15;
            if (col >= Fstore) continue;
            float bv = (col < Freal) ? (isC ? biasC[col] : biasL[col]) : 0.f;
#pragma unroll
            for (int s = 0; s < 2; ++s)
#pragma unroll
                for (int j = 0; j < 4; ++j) {
                    int rowo = row0 + wr * 32 + s * 16 + (lane >> 4) * 4 + j;
                    float v = acc[s][u][j] + bv;
                    if (RELU) v = fmaxf(v, 0.f);
                    size_t oi = (size_t)rowo * Fstore + col;
                    if (OUTM == 1) {
                        short h = f2bf(v);
                        OH[oi] = h;
                        OL[oi] = f2bf(v - bf2f(h));
                    } else {
                        ((_Float16*)OF)[oi] = (_Float16)v;
                    }
                }
        }
    } else {
        // Fused LSTM epilogue (R5-R7 verified). colp = permuted gate col 4j+g.
        const int ql = lane & 3;
#pragma unroll
        for (int u = 0; u < 2; ++u) {
            int colp = c0 + wc * 32 + u * 16 + l15;
            int wrr = (colp & 3) * 128 + (colp >> 2);
            float bv = isC ? biasC[wrr] : biasL[wrr];
            int j = colp >> 2;
#pragma unroll
            for (int s = 0; s < 2; ++s) {
                float ii = 0.f, ff = 0.f, gg = 0.f, oo = 0.f;
#pragma unroll
                for (int r2 = 0; r2 < 4; ++r2) {
                    float v0 = acc[s][u][r2] + bv;
                    float x1 = __shfl_xor(v0, 1);
                    float x2 = __shfl_xor(v0, 2);
                    float x3 = __shfl_xor(v0, 3);
                    float iv = (ql == 0) ? v0 : (ql == 1) ? x1 : (ql == 2) ? x2 : x3;
                    float fv = (ql == 0) ? x1 : (ql == 1) ? v0 : (ql == 2) ? x3 : x2;
                    float gv = (ql == 0) ? x2 : (ql == 1) ? x3 : (ql == 2) ? v0 : x1;
                    float ov = (ql == 0) ? x3 : (ql == 1) ? x2 : (ql == 2) ? x1 : v0;
                    if (ql == r2) { ii = iv; ff = fv; gg = gv; oo = ov; }
                }
                int rowo = row0 + wr * 32 + s * 16 + (lane >> 4) * 4 + ql;
                size_t ci = (size_t)rowo * 128 + j;
                float c2 = sigf(ff) * Cold[ci] + sigf(ii) * tanhf(gg);
                float h2 = sigf(oo) * tanhf(c2);
                Cnew[ci] = c2;
                short h = f2bf(h2);
                OH[ci] = h;
                OL[ci] = f2bf(h2 - bf2f(h));
            }
        }
    }
}

// ---------------------------------------------------------------------------
// SpMM gather: fp16 X in (R7-verified numerics), fp32 acc, split-bf16 out.
// ---------------------------------------------------------------------------
__global__ __launch_bounds__(256) void spmm_kernel(
    const int* __restrict__ Lp, const int* __restrict__ Li,
    const int* __restrict__ Tp, const int* __restrict__ Ti,
    const _Float16* __restrict__ X, short* __restrict__ mh, short* __restrict__ ml)
{
    const int r = blockIdx.x * 4 + (threadIdx.x >> 6);
    const int cp = (threadIdx.x & 63) * 2;
    if (r >= NRREAL) return;
    float s0 = 0.f, s1 = 0.f;
    if (r < NL) {
        int b = Lp[r], e = Lp[r + 1];
        int i = b;
        for (; i + 3 < e; i += 4) {
            unsigned u0 = *(const unsigned*)&X[(size_t)(ROWC0 + Li[i]) * EMB + cp];
            unsigned u1 = *(const unsigned*)&X[(size_t)(ROWC0 + Li[i + 1]) * EMB + cp];
            unsigned u2 = *(const unsigned*)&X[(size_t)(ROWC0 + Li[i + 2]) * EMB + cp];
            unsigned u3 = *(const unsigned*)&X[(size_t)(ROWC0 + Li[i + 3]) * EMB + cp];
            float2 v0 = h2f2(u0), v1 = h2f2(u1), v2 = h2f2(u2), v3 = h2f2(u3);
            s0 += v0.x + v1.x + v2.x + v3.x;
            s1 += v0.y + v1.y + v2.y + v3.y;
        }
        for (; i < e; ++i) {
            float2 v = h2f2(*(const unsigned*)&X[(size_t)(ROWC0 + Li[i]) * EMB + cp]);
            s0 += v.x; s1 += v.y;
        }
    } else if (r >= ROWC0) {
        int c = r - ROWC0;
        int b = Tp[c], e = Tp[c + 1];
        int i = b;
        for (; i + 3 < e; i += 4) {
            unsigned u0 = *(const unsigned*)&X[(size_t)Ti[i] * EMB + cp];
            unsigned u1 = *(const unsigned*)&X[(size_t)Ti[i + 1] * EMB + cp];
            unsigned u2 = *(const unsigned*)&X[(size_t)Ti[i + 2] * EMB + cp];
            unsigned u3 = *(const unsigned*)&X[(size_t)Ti[i + 3] * EMB + cp];
            float2 v0 = h2f2(u0), v1 = h2f2(u1), v2 = h2f2(u2), v3 = h2f2(u3);
            s0 += v0.x + v1.x + v2.x + v3.x;
            s1 += v0.y + v1.y + v2.y + v3.y;
        }
        for (; i < e; ++i) {
            float2 v = h2f2(*(const unsigned*)&X[(size_t)Ti[i] * EMB + cp]);
            s0 += v.x; s1 += v.y;
        }
    } else {
        return;
    }
    size_t oi = (size_t)r * EMB + cp;
    short h0 = f2bf(s0), h1 = f2bf(s1);
    *(unsigned*)&mh[oi] = (unsigned)(unsigned short)h0 | ((unsigned)(unsigned short)h1 << 16);
    short l0 = f2bf(s0 - bf2f(h0)), l1 = f2bf(s1 - bf2f(h1));
    *(unsigned*)&ml[oi] = (unsigned)(unsigned short)l0 | ((unsigned)(unsigned short)l1 << 16);
}

__global__ __launch_bounds__(256) void init_states(
    const float* __restrict__ Li, const float* __restrict__ Ci,
    short* __restrict__ Hh, short* __restrict__ Hl, float* __restrict__ C,
    short* __restrict__ msgsH, short* __restrict__ msgsL, float* __restrict__ accum)
{
    size_t idx = (size_t)blockIdx.x * 256 + threadIdx.x;
    if (idx >= (size_t)NRP * EMB) return;
    int r = (int)(idx >> 7);
    int e = (int)(idx & 127);
    float h = 0.f;
    if (r < NL) h = Li[e];
    else if (r >= ROWC0 && r < NRREAL) h = Ci[e];
    short hh = f2bf(h);
    Hh[idx] = hh;
    Hl[idx] = f2bf(h - bf2f(hh));
    C[idx] = 0.f;
    if (r >= NRREAL || (r >= NL && r < ROWC0)) { msgsH[idx] = 0; msgsL[idx] = 0; }
    if (idx == 0) accum[0] = 0.f;
}

// ---------------------------------------------------------------------------
// Merged weight split (1 dispatch; verified R9/R10). perm = LSTM gate perm.
// ---------------------------------------------------------------------------
struct SplitJobs {
    const float* src[12];
    short* dh[12]; short* dl[12];
    int rows[12], cols[12], prows[12], pcols[12], perm[12];
};

__global__ __launch_bounds__(256) void split_all(SplitJobs J)
{
    int j = blockIdx.y;
    int i = blockIdx.x * 256 + threadIdx.x;
    int pr = J.prows[j], pc = J.pcols[j];
    if (i >= pr * pc) return;
    int pp = i / pc, c = i - pp * pc;
    int r = J.perm[j] ? (((pp & 3) << 7) | (pp >> 2)) : pp;
    float v = (r < J.rows[j] && c < J.cols[j]) ? J.src[j][(size_t)r * J.cols[j] + c] : 0.f;
    short h = f2bf(v);
    J.dh[j][i] = h;
    J.dl[j][i] = f2bf(v - bf2f(h));
}

// ---------------------------------------------------------------------------
// CSR build (verified rounds 1-10)
// ---------------------------------------------------------------------------
__global__ __launch_bounds__(256) void count_rows_L(const float* __restrict__ M, int* __restrict__ cnt)
{
    int l = blockIdx.x, t = threadIdx.x;
    int c_ = 0;
    for (int c = t; c < NC; c += 256) c_ += (M[(size_t)l * NC + c] != 0.f) ? 1 : 0;
#pragma unroll
    for (int off = 32; off > 0; off >>= 1) c_ += __shfl_down(c_, off);
    __shared__ int w[4];
    if ((t & 63) == 0) w[t >> 6] = c_;
    __syncthreads();
    if (t == 0) cnt[l] = w[0] + w[1] + w[2] + w[3];
}

__global__ __launch_bounds__(256) void scan_excl(const int* __restrict__ in, int* __restrict__ out, int n)
{
    const int t = threadIdx.x;
    const int per = (n + 255) >> 8;
    __shared__ int part[256];
    int s = 0;
    const int start = t * per;
    for (int i = 0; i < per; ++i) { int idx = start + i; if (idx < n) s += in[idx]; }
    part[t] = s;
    __syncthreads();
    for (int off = 1; off < 256; off <<= 1) {
        int v = (t >= off) ? part[t - off] : 0;
        __syncthreads();
        part[t] += v;
        __syncthreads();
    }
    int run = (t == 0) ? 0 : part[t - 1];
    for (int i = 0; i < per; ++i) {
        int idx = start + i;
        if (idx < n) { out[idx] = run; run += in[idx]; }
    }
    if (t == 255) out[n] = part[255];
}

__global__ __launch_bounds__(256) void fill_L(const float* __restrict__ M,
                                              const int* __restrict__ Lp, int* __restrict__ Lidx)
{
    int l = blockIdx.x, t = threadIdx.x, lane = t & 63, wid = t >> 6;
    __shared__ int wcnt[4];
    __shared__ int base;
    if (t == 0) base = Lp[l];
    __syncthreads();
    for (int c0 = 0; c0 < NC; c0 += 256) {
        int c = c0 + t;
        bool pr = (c < NC) && (M[(size_t)l * NC + c] != 0.f);
        unsigned long long m = __ballot(pr);
        if (lane == 0) wcnt[wid] = (int)__popcll(m);
        __syncthreads();
        int off = base;
        for (int w = 0; w < wid; ++w) off += wcnt[w];
        int rank = (int)__popcll(m & ((1ull << lane) - 1ull));
        if (pr) Lidx[off + rank] = c;
        __syncthreads();
        if (t == 0) base += wcnt[0] + wcnt[1] + wcnt[2] + wcnt[3];
        __syncthreads();
    }
}

__global__ __launch_bounds__(256) void count_T(const float* __restrict__ M, int* __restrict__ cnt2d)
{
    int s = blockIdx.y;
    int c = blockIdx.x * 256 + threadIdx.x;
    if (c >= NC) return;
    int n = 0;
    int l0 = s * LCHUNK, l1 = l0 + LCHUNK;
    for (int l = l0; l < l1; ++l) n += (M[(size_t)l * NC + c] != 0.f) ? 1 : 0;
    cnt2d[(size_t)s * NC + c] = n;
}

__global__ __launch_bounds__(256) void colscan_T(const int* __restrict__ cnt2d,
                                                 int* __restrict__ cum2d, int* __restrict__ cntT)
{
    int c = blockIdx.x * 256 + threadIdx.x;
    if (c >= NC) return;
    int run = 0;
    for (int s = 0; s < NCHUNK; ++s) {
        cum2d[(size_t)s * NC + c] = run;
        run += cnt2d[(size_t)s * NC + c];
    }
    cntT[c] = run;
}

__global__ __launch_bounds__(256) void fill_T(const float* __restrict__ M,
                                              const int* __restrict__ Tp, const int* __restrict__ cum2d,
                                              int* __restrict__ Tidx)
{
    int s = blockIdx.y;
    int c = blockIdx.x * 256 + threadIdx.x;
    if (c >= NC) return;
    int pos = Tp[c] + cum2d[(size_t)s * NC + c];
    int l0 = s * LCHUNK, l1 = l0 + LCHUNK;
    for (int l = l0; l < l1; ++l) {
        if (M[(size_t)l * NC + c] != 0.f) Tidx[pos++] = l;
    }
}

// ---------------------------------------------------------------------------
// Vote epilogue
// ---------------------------------------------------------------------------
__global__ __launch_bounds__(256) void vote_reduce(
    const short* __restrict__ H2h, const short* __restrict__ H2l,
    const float* __restrict__ W3, const float* __restrict__ b3, float* __restrict__ accum)
{
    int wid = threadIdx.x >> 6, lane = threadIdx.x & 63;
    int r = blockIdx.x * 4 + wid;
    float s = 0.f;
    if (r < NL) {
        const short* xh = &H2h[(size_t)r * 224];
        const short* xl = &H2l[(size_t)r * 224];
        for (int k = lane; k < 200; k += 64) s += (bf2f(xh[k]) + bf2f(xl[k])) * W3[k];
    }
#pragma unroll
    for (int off = 32; off > 0; off >>= 1) s += __shfl_down(s, off);
    if (lane == 0 && r < NL) {
        float v = 1.f / (1.f + expf(-(s + b3[0])));
        atomicAdd(accum, v);
    }
}

__global__ void finalize_logit(const float* __restrict__ accum, float* __restrict__ out)
{
    float avg = accum[0] / (float)NL;
    out[0] = logf(avg / (1.f - avg));
}

// ---------------------------------------------------------------------------
// Host launcher (R7 multi-kernel structure — the measured best)
// ---------------------------------------------------------------------------
extern "C" void kernel_launch(void* const* d_in, const int* in_sizes, int n_in,
                              void* d_out, int out_size, void* d_ws, size_t ws_size,
                              hipStream_t stream)
{
    const float* M      = (const float*)d_in[0];
    const float* L_init = (const float*)d_in[1];
    const float* C_init = (const float*)d_in[2];
    const float* LC_W1 = (const float*)d_in[3];  const float* LC_b1 = (const float*)d_in[4];
    const float* LC_W2 = (const float*)d_in[5];  const float* LC_b2 = (const float*)d_in[6];
    const float* LC_W3 = (const float*)d_in[7];  const float* LC_b3 = (const float*)d_in[8];
    const float* CL_W1 = (const float*)d_in[9];  const float* CL_b1 = (const float*)d_in[10];
    const float* CL_W2 = (const float*)d_in[11]; const float* CL_b2 = (const float*)d_in[12];
    const float* CL_W3 = (const float*)d_in[13]; const float* CL_b3 = (const float*)d_in[14];
    const float* L_Wih = (const float*)d_in[15]; const float* L_Whh = (const float*)d_in[16];
    const float* L_b   = (const float*)d_in[17];
    const float* C_Wih = (const float*)d_in[18]; const float* C_Whh = (const float*)d_in[19];
    const float* C_b   = (const float*)d_in[20];
    const float* V_W1 = (const float*)d_in[21]; const float* V_b1 = (const float*)d_in[22];
    const float* V_W2 = (const float*)d_in[23]; const float* V_b2 = (const float*)d_in[24];
    const float* V_W3 = (const float*)d_in[25]; const float* V_b3 = (const float*)d_in[26];
    float* out = (float*)d_out;

    char* ws = (char*)d_ws;
    size_t off = 0;
    auto alloc = [&](size_t bytes) -> void* {
        void* pt = ws + off;
        off += (bytes + 255) & ~(size_t)255;
        return pt;
    };
    const size_t NE = (size_t)NRP * EMB;
    short* HAh = (short*)alloc(NE * 2); short* HAl = (short*)alloc(NE * 2);
    short* HBh = (short*)alloc(NE * 2); short* HBl = (short*)alloc(NE * 2);
    float* CA = (float*)alloc(NE * 4);  float* CB = (float*)alloc(NE * 4);
    short* msgsH = (short*)alloc(NE * 2); short* msgsL = (short*)alloc(NE * 2);
    _Float16* X = (_Float16*)alloc(NE * 2);
    short* H1h = (short*)alloc((size_t)NRP * 416 * 2); short* H1l = (short*)alloc((size_t)NRP * 416 * 2);
    short* H2h = (short*)alloc((size_t)NRP * 224 * 2); short* H2l = (short*)alloc((size_t)NRP * 224 * 2);
    float* accum = (float*)alloc(256);
    // split/padded weights (B rows padded so any 64-col tile is in-bounds)
    short* W1hL = (short*)alloc(512 * 128 * 2); short* W1lL = (short*)alloc(512 * 128 * 2);
    short* W1hC = (short*)alloc(512 * 128 * 2); short* W1lC = (short*)alloc(512 * 128 * 2);
    short* W2hL = (short*)alloc(256 * 416 * 2); short* W2lL = (short*)alloc(256 * 416 * 2);
    short* W2hC = (short*)alloc(256 * 416 * 2); short* W2lC = (short*)alloc(256 * 416 * 2);
    short* W3hL = (short*)alloc(128 * 224 * 2); short* W3lL = (short*)alloc(128 * 224 * 2);
    short* W3hC = (short*)alloc(128 * 224 * 2); short* W3lC = (short*)alloc(128 * 224 * 2);
    short* WihhL = (short*)alloc(512 * 128 * 2); short* WihlL = (short*)alloc(512 * 128 * 2);
    short* WhhhL = (short*)alloc(512 * 128 * 2); short* WhhlL = (short*)alloc(512 * 128 * 2);
    short* WihhC = (short*)alloc(512 * 128 * 2); short* WihlC = (short*)alloc(512 * 128 * 2);
    short* WhhhC = (short*)alloc(512 * 128 * 2); short* WhhlC = (short*)alloc(512 * 128 * 2);
    short* V1h = (short*)alloc(512 * 128 * 2); short* V1l = (short*)alloc(512 * 128 * 2);
    short* V2h = (short*)alloc(256 * 416 * 2); short* V2l = (short*)alloc(256 * 416 * 2);
    // CSR
    int* Lp   = (int*)alloc(4104 * 4);
    int* Tp   = (int*)alloc(8104 * 4);
    int* Lidx = (int*)alloc(1000000 * 4);
    int* Tidx = (int*)alloc(1000000 * 4);
    int* cnt2d = (int*)alloc((size_t)NCHUNK * NC * 4);
    int* cum2d = (int*)alloc((size_t)NCHUNK * NC * 4);
    int* cntL = (int*)alloc(4096 * 4);
    int* cntT = (int*)alloc(8192 * 4);
    (void)ws_size; (void)in_sizes; (void)n_in; (void)out_size;

    // --- CSR build ---
    count_rows_L<<<NL, 256, 0, stream>>>(M, cntL);
    scan_excl<<<1, 256, 0, stream>>>(cntL, Lp, NL);
    fill_L<<<NL, 256, 0, stream>>>(M, Lp, Lidx);
    {
        dim3 g((NC + 255) / 256, NCHUNK);
        count_T<<<g, 256, 0, stream>>>(M, cnt2d);
        colscan_T<<<(NC + 255) / 256, 256, 0, stream>>>(cnt2d, cum2d, cntT);
        scan_excl<<<1, 256, 0, stream>>>(cntT, Tp, NC);
        fill_T<<<g, 256, 0, stream>>>(M, Tp, cum2d, Tidx);
    }

    // --- merged weight split (1 dispatch) ---
    SplitJobs Jb{};
    auto setj = [&](int j, const float* s, short* dh, short* dl, int r, int c, int pr, int pc, int pm) {
        Jb.src[j] = s; Jb.dh[j] = dh; Jb.dl[j] = dl;
        Jb.rows[j] = r; Jb.cols[j] = c; Jb.prows[j] = pr; Jb.pcols[j] = pc; Jb.perm[j] = pm;
    };
    setj(0, LC_W1, W1hL, W1lL, 400, 128, 512, 128, 0);
    setj(1, CL_W1, W1hC, W1lC, 400, 128, 512, 128, 0);
    setj(2, LC_W2, W2hL, W2lL, 200, 400, 256, 416, 0);
    setj(3, CL_W2, W2hC, W2lC, 200, 400, 256, 416, 0);
    setj(4, LC_W3, W3hL, W3lL, 128, 200, 128, 224, 0);
    setj(5, CL_W3, W3hC, W3lC, 128, 200, 128, 224, 0);
    setj(6, L_Wih, WihhL, WihlL, 512, 128, 512, 128, 1);
    setj(7, L_Whh, WhhhL, WhhlL, 512, 128, 512, 128, 1);
    setj(8, C_Wih, WihhC, WihlC, 512, 128, 512, 128, 1);
    setj(9, C_Whh, WhhhC, WhhlC, 512, 128, 512, 128, 1);
    setj(10, V_W1, V1h, V1l, 400, 128, 512, 128, 0);
    setj(11, V_W2, V2h, V2l, 200, 400, 256, 416, 0);
    {
        dim3 g((106496 + 255) / 256, 12);
        split_all<<<g, 256, 0, stream>>>(Jb);
    }

    const int nelem_blocks = (int)((NE + 255) / 256);
    init_states<<<nelem_blocks, 256, 0, stream>>>(L_init, C_init, HAh, HAl, CA, msgsH, msgsL, accum);

    // --- 30 message-passing steps (5 kernels each) ---
    short *Hch = HAh, *Hcl = HAl, *Hnh = HBh, *Hnl = HBl;
    float *Ccur = CA, *Cnxt = CB;
    for (int step = 0; step < TSTEPS; ++step) {
        gemm64<128, 1, false, true><<<dim3(7, 192), 256, 0, stream>>>(
            Hch, Hcl, nullptr, nullptr,
            W1hL, W1lL, W1hC, W1lC, nullptr, nullptr, nullptr, nullptr,
            LC_b1, CL_b1, H1h, H1l, nullptr, nullptr, nullptr, 400, 416);
        gemm64<416, 1, false, true><<<dim3(4, 192), 256, 0, stream>>>(
            H1h, H1l, nullptr, nullptr,
            W2hL, W2lL, W2hC, W2lC, nullptr, nullptr, nullptr, nullptr,
            LC_b2, CL_b2, H2h, H2l, nullptr, nullptr, nullptr, 200, 224);
        gemm64<224, 4, false, false><<<dim3(2, 192), 256, 0, stream>>>(
            H2h, H2l, nullptr, nullptr,
            W3hL, W3lL, W3hC, W3lC, nullptr, nullptr, nullptr, nullptr,
            LC_b3, CL_b3, nullptr, nullptr, (float*)X, nullptr, nullptr, 128, 128);
        spmm_kernel<<<(NRREAL + 3) / 4, 256, 0, stream>>>(Lp, Lidx, Tp, Tidx, X, msgsH, msgsL);
        gemm64<128, 3, true, false><<<dim3(8, 192), 256, 0, stream>>>(
            msgsH, msgsL, Hch, Hcl,
            WihhL, WihlL, WihhC, WihlC, WhhhL, WhhlL, WhhhC, WhhlC,
            L_b, C_b, Hnh, Hnl, nullptr, Ccur, Cnxt, 512, 512);
        short* th = Hch; Hch = Hnh; Hnh = th;
        short* tl = Hcl; Hcl = Hnl; Hnl = tl;
        float* tc = Ccur; Ccur = Cnxt; Cnxt = tc;
    }

    // --- vote MLP + logit (lit rows only: 64 row panels of 64) ---
    gemm64<128, 1, false, true><<<dim3(7, 64), 256, 0, stream>>>(
        Hch, Hcl, nullptr, nullptr,
        V1h, V1l, V1h, V1l, nullptr, nullptr, nullptr, nullptr,
        V_b1, V_b1, H1h, H1l, nullptr, nullptr, nullptr, 400, 416);
    gemm64<416, 1, false, true><<<dim3(4, 64), 256, 0, stream>>>(
        H1h, H1l, nullptr, nullptr,
        V2h, V2l, V2h, V2l, nullptr, nullptr, nullptr, nullptr,
        V_b2, V_b2, H2h, H2l, nullptr, nullptr, nullptr, 200, 224);
    vote_reduce<<<(NL + 3) / 4, 256, 0, stream>>>(H2h, H2l, V_W3, V_b3, accum);
    finalize_logit<<<1, 1, 0, stream>>>(accum, out);
}

// Round 12
// 3056.305 us; speedup vs baseline: 5.9061x; 1.1663x over previous
//
#include <hip/hip_runtime.h>

#define NL 4000
#define NC 8000
#define EMB 128
#define ROWC0 4096           // clause region start (64-aligned)
#define NRP 12288            // padded total rows (192 x 64)
#define NRREAL (ROWC0 + NC)  // 12096 rows with data
#define TSTEPS 30
#define LCHUNK 80
#define NCHUNK 50

typedef __attribute__((ext_vector_type(8))) short bf16x8;
typedef __attribute__((ext_vector_type(4))) float f32x4;

__device__ __forceinline__ short f2bf(float x) {
    union { float f; unsigned u; } v; v.f = x;
    unsigned r = v.u + 0x7fffu + ((v.u >> 16) & 1u);
    return (short)(r >> 16);
}
__device__ __forceinline__ float bf2f(short s) {
    union { unsigned u; float f; } v; v.u = ((unsigned)(unsigned short)s) << 16;
    return v.f;
}
__device__ __forceinline__ float sigf(float x) { return 1.f / (1.f + expf(-x)); }
__device__ __forceinline__ float2 h2f2(unsigned u) {
    union { unsigned v; _Float16 h[2]; } x; x.v = u;
    return make_float2((float)x.h[0], (float)x.h[1]);
}
__device__ __forceinline__ void gload16(const void* g, void* l) {
    __builtin_amdgcn_global_load_lds(
        (const __attribute__((address_space(1))) unsigned int*)g,
        (__attribute__((address_space(3))) unsigned int*)l, 16, 0, 0);
}

// ---------------------------------------------------------------------------
// Split-bf16 MFMA GEMM, 64x64 tile, 256 thr (4 waves 2x2, wave-tile 32x32).
// R11-verified single-buffer 128-K mega-chunk staging (measured best).
// NEW (R12): 1-D grid + bijective XCD-chunked swizzle (T1/m204) — tx varies
// fastest within an XCD so each XCD sweeps whole row panels (A stays in its
// private L2). gridDim.x must be divisible by 8 (all launches are).
// product = Ah*Wh + Ah*Wl + Al*Wh in fp32 acc (R2-R11 verified numerics).
// OUTM: 1 = split-bf16 out (+relu), 4 = fp16 out, 3 = fused LSTM epilogue.
// ---------------------------------------------------------------------------
template<int KS, int OUTM, bool TWOA, bool RELU>
__global__ __launch_bounds__(256) void gemm64(
    const short* __restrict__ A1h, const short* __restrict__ A1l,
    const short* __restrict__ A2h, const short* __restrict__ A2l,
    const short* __restrict__ B1hL, const short* __restrict__ B1lL,
    const short* __restrict__ B1hC, const short* __restrict__ B1lC,
    const short* __restrict__ B2hL, const short* __restrict__ B2lL,
    const short* __restrict__ B2hC, const short* __restrict__ B2lC,
    const float* __restrict__ biasL, const float* __restrict__ biasC,
    short* __restrict__ OH, short* __restrict__ OL, float* __restrict__ OF,
    const float* __restrict__ Cold, float* __restrict__ Cnew,
    int Freal, int Fstore, int nx)
{
    __shared__ short sAh[4 * 2048];   // [chunk32 q][row 64][32] per split
    __shared__ short sAl[4 * 2048];
    __shared__ short sBh[4 * 2048];
    __shared__ short sBl[4 * 2048];

    // XCD-chunked bijective swizzle (total % 8 == 0 for every launch)
    const int flat = blockIdx.x;
    const int qx = (int)gridDim.x >> 3;
    const int wg = (flat & 7) * qx + (flat >> 3);
    const int row0 = (wg / nx) * 64;
    const int c0 = (wg % nx) * 64;
    const bool isC = (row0 >= ROWC0);
    const int t = threadIdx.x;
    const int lane = t & 63;
    const int w = t >> 6;
    const int wr = w >> 1, wc = w & 1;
    const int l15 = lane & 15;

    f32x4 acc[2][2] = {};
    bool first = true;

    const int nph = TWOA ? 2 : 1;
    for (int ph = 0; ph < nph; ++ph) {
        const short* Ah = (TWOA && ph) ? A2h : A1h;
        const short* Al = (TWOA && ph) ? A2l : A1l;
        const short* Bh = (TWOA && ph) ? (isC ? B2hC : B2hL) : (isC ? B1hC : B1hL);
        const short* Bl = (TWOA && ph) ? (isC ? B2lC : B2lL) : (isC ? B1lC : B1lL);

        for (int kc0 = 0; kc0 < KS; kc0 += 128) {
            const int n32 = ((KS - kc0) >> 5) < 4 ? ((KS - kc0) >> 5) : 4;
            if (!first) __syncthreads();   // buffer free (prev chunk consumed)
            first = false;
            const int row = t >> 2, slot = t & 3;
#pragma unroll 4
            for (int q = 0; q < n32; ++q) {
                int gk = kc0 + q * 32 + ((slot ^ ((row >> 1) & 3)) << 3);
                size_t ga = (size_t)(row0 + row) * KS + gk;
                size_t gb = (size_t)(c0 + row) * KS + gk;
                gload16(Ah + ga, &sAh[q * 2048 + t * 8]);
                gload16(Al + ga, &sAl[q * 2048 + t * 8]);
                gload16(Bh + gb, &sBh[q * 2048 + t * 8]);
                gload16(Bl + gb, &sBl[q * 2048 + t * 8]);
            }
            asm volatile("s_waitcnt vmcnt(0)" ::: "memory");
            __syncthreads();
#pragma unroll 4
            for (int q = 0; q < n32; ++q) {
                bf16x8 af[2][2], bf[2][2];
#pragma unroll
                for (int s = 0; s < 2; ++s) {
                    int ar = wr * 32 + s * 16 + l15;
                    int aslot = (lane >> 4) ^ ((ar >> 1) & 3);
                    int ai = q * 2048 + ar * 32 + aslot * 8;
                    af[s][0] = *(const bf16x8*)&sAh[ai];
                    af[s][1] = *(const bf16x8*)&sAl[ai];
                    int br = wc * 32 + s * 16 + l15;
                    int bslot = (lane >> 4) ^ ((br >> 1) & 3);
                    int bi = q * 2048 + br * 32 + bslot * 8;
                    bf[s][0] = *(const bf16x8*)&sBh[bi];
                    bf[s][1] = *(const bf16x8*)&sBl[bi];
                }
#pragma unroll
                for (int s = 0; s < 2; ++s)
#pragma unroll
                    for (int u = 0; u < 2; ++u) {
                        acc[s][u] = __builtin_amdgcn_mfma_f32_16x16x32_bf16(af[s][0], bf[u][0], acc[s][u], 0, 0, 0);
                        acc[s][u] = __builtin_amdgcn_mfma_f32_16x16x32_bf16(af[s][0], bf[u][1], acc[s][u], 0, 0, 0);
                        acc[s][u] = __builtin_amdgcn_mfma_f32_16x16x32_bf16(af[s][1], bf[u][0], acc[s][u], 0, 0, 0);
                    }
            }
        }
    }

    if (OUTM != 3) {
        // C/D frag layout: col = lane&15, row = (lane>>4)*4 + reg (m89)
#pragma unroll
        for (int u = 0; u < 2; ++u) {
            int col = c0 + wc * 32 + u * 16 + l15;
            if (col >= Fstore) continue;
            float bv = (col < Freal) ? (isC ? biasC[col] : biasL[col]) : 0.f;
#pragma unroll
            for (int s = 0; s < 2; ++s)
#pragma unroll
                for (int j = 0; j < 4; ++j) {
                    int rowo = row0 + wr * 32 + s * 16 + (lane >> 4) * 4 + j;
                    float v = acc[s][u][j] + bv;
                    if (RELU) v = fmaxf(v, 0.f);
                    size_t oi = (size_t)rowo * Fstore + col;
                    if (OUTM == 1) {
                        short h = f2bf(v);
                        OH[oi] = h;
                        OL[oi] = f2bf(v - bf2f(h));
                    } else {
                        ((_Float16*)OF)[oi] = (_Float16)v;
                    }
                }
        }
    } else {
        // Fused LSTM epilogue (R5-R11 verified). colp = permuted gate col 4j+g.
        const int ql = lane & 3;
#pragma unroll
        for (int u = 0; u < 2; ++u) {
            int colp = c0 + wc * 32 + u * 16 + l15;
            int wrr = (colp & 3) * 128 + (colp >> 2);
            float bv = isC ? biasC[wrr] : biasL[wrr];
            int j = colp >> 2;
#pragma unroll
            for (int s = 0; s < 2; ++s) {
                float ii = 0.f, ff = 0.f, gg = 0.f, oo = 0.f;
#pragma unroll
                for (int r2 = 0; r2 < 4; ++r2) {
                    float v0 = acc[s][u][r2] + bv;
                    float x1 = __shfl_xor(v0, 1);
                    float x2 = __shfl_xor(v0, 2);
                    float x3 = __shfl_xor(v0, 3);
                    float iv = (ql == 0) ? v0 : (ql == 1) ? x1 : (ql == 2) ? x2 : x3;
                    float fv = (ql == 0) ? x1 : (ql == 1) ? v0 : (ql == 2) ? x3 : x2;
                    float gv = (ql == 0) ? x2 : (ql == 1) ? x3 : (ql == 2) ? v0 : x1;
                    float ov = (ql == 0) ? x3 : (ql == 1) ? x2 : (ql == 2) ? x1 : v0;
                    if (ql == r2) { ii = iv; ff = fv; gg = gv; oo = ov; }
                }
                int rowo = row0 + wr * 32 + s * 16 + (lane >> 4) * 4 + ql;
                size_t ci = (size_t)rowo * 128 + j;
                float c2 = sigf(ff) * Cold[ci] + sigf(ii) * tanhf(gg);
                float h2 = sigf(oo) * tanhf(c2);
                Cnew[ci] = c2;
                short h = f2bf(h2);
                OH[ci] = h;
                OL[ci] = f2bf(h2 - bf2f(h));
            }
        }
    }
}

// ---------------------------------------------------------------------------
// SpMM gather (R12): 4-edge-parallel. Wave = 1 output row; 4 edge-groups x
// 16 lanes; each lane one dwordx4 (8 fp16 cols) with 1-deep prefetch;
// final shfl_xor(16/32) fold. fp32 acc (reassoc only), split-bf16 out.
// ---------------------------------------------------------------------------
__global__ __launch_bounds__(256) void spmm_kernel(
    const int* __restrict__ Lp, const int* __restrict__ Li,
    const int* __restrict__ Tp, const int* __restrict__ Ti,
    const _Float16* __restrict__ X, short* __restrict__ mh, short* __restrict__ ml)
{
    const int r = blockIdx.x * 4 + (threadIdx.x >> 6);
    const int lane = threadIdx.x & 63;
    const int eg = lane >> 4;       // edge group 0..3
    const int cl = lane & 15;       // col slot (8 fp16 each)
    if (r >= NRREAL) return;
    const int cp = cl * 8;

    int b, e, base;
    const int* idx;
    if (r < NL) { b = Lp[r]; e = Lp[r + 1]; idx = Li; base = ROWC0; }
    else if (r >= ROWC0) { int c = r - ROWC0; b = Tp[c]; e = Tp[c + 1]; idx = Ti; base = 0; }
    else return;

    float s0 = 0.f, s1 = 0.f, s2 = 0.f, s3 = 0.f, s4 = 0.f, s5 = 0.f, s6 = 0.f, s7 = 0.f;
    int i = b + eg;
    bool has = i < e;
    uint4 v = make_uint4(0, 0, 0, 0);
    if (has) v = *(const uint4*)&X[(size_t)(base + idx[i]) * EMB + cp];
    while (has) {
        int in_ = i + 4;
        bool hn = in_ < e;
        uint4 vn = v;
        if (hn) vn = *(const uint4*)&X[(size_t)(base + idx[in_]) * EMB + cp];
        float2 f0 = h2f2(v.x), f1 = h2f2(v.y), f2 = h2f2(v.z), f3 = h2f2(v.w);
        s0 += f0.x; s1 += f0.y; s2 += f1.x; s3 += f1.y;
        s4 += f2.x; s5 += f2.y; s6 += f3.x; s7 += f3.y;
        v = vn; i = in_; has = hn;
    }
    // fold the 4 edge groups
    s0 += __shfl_xor(s0, 16); s0 += __shfl_xor(s0, 32);
    s1 += __shfl_xor(s1, 16); s1 += __shfl_xor(s1, 32);
    s2 += __shfl_xor(s2, 16); s2 += __shfl_xor(s2, 32);
    s3 += __shfl_xor(s3, 16); s3 += __shfl_xor(s3, 32);
    s4 += __shfl_xor(s4, 16); s4 += __shfl_xor(s4, 32);
    s5 += __shfl_xor(s5, 16); s5 += __shfl_xor(s5, 32);
    s6 += __shfl_xor(s6, 16); s6 += __shfl_xor(s6, 32);
    s7 += __shfl_xor(s7, 16); s7 += __shfl_xor(s7, 32);

    if (eg == 0) {
        float sv[8] = { s0, s1, s2, s3, s4, s5, s6, s7 };
        unsigned hp[4], lp[4];
#pragma unroll
        for (int j = 0; j < 4; ++j) {
            short ha = f2bf(sv[2 * j]), hb = f2bf(sv[2 * j + 1]);
            hp[j] = (unsigned)(unsigned short)ha | ((unsigned)(unsigned short)hb << 16);
            short la = f2bf(sv[2 * j] - bf2f(ha)), lb = f2bf(sv[2 * j + 1] - bf2f(hb));
            lp[j] = (unsigned)(unsigned short)la | ((unsigned)(unsigned short)lb << 16);
        }
        size_t oi = (size_t)r * EMB + cp;
        *(uint4*)&mh[oi] = make_uint4(hp[0], hp[1], hp[2], hp[3]);
        *(uint4*)&ml[oi] = make_uint4(lp[0], lp[1], lp[2], lp[3]);
    }
}

__global__ __launch_bounds__(256) void init_states(
    const float* __restrict__ Li, const float* __restrict__ Ci,
    short* __restrict__ Hh, short* __restrict__ Hl, float* __restrict__ C,
    short* __restrict__ msgsH, short* __restrict__ msgsL, float* __restrict__ accum)
{
    size_t idx = (size_t)blockIdx.x * 256 + threadIdx.x;
    if (idx >= (size_t)NRP * EMB) return;
    int r = (int)(idx >> 7);
    int e = (int)(idx & 127);
    float h = 0.f;
    if (r < NL) h = Li[e];
    else if (r >= ROWC0 && r < NRREAL) h = Ci[e];
    short hh = f2bf(h);
    Hh[idx] = hh;
    Hl[idx] = f2bf(h - bf2f(hh));
    C[idx] = 0.f;
    if (r >= NRREAL || (r >= NL && r < ROWC0)) { msgsH[idx] = 0; msgsL[idx] = 0; }
    if (idx == 0) accum[0] = 0.f;
}

// ---------------------------------------------------------------------------
// Merged weight split (1 dispatch; verified). perm = LSTM gate permutation.
// ---------------------------------------------------------------------------
struct SplitJobs {
    const float* src[12];
    short* dh[12]; short* dl[12];
    int rows[12], cols[12], prows[12], pcols[12], perm[12];
};

__global__ __launch_bounds__(256) void split_all(SplitJobs J)
{
    int j = blockIdx.y;
    int i = blockIdx.x * 256 + threadIdx.x;
    int pr = J.prows[j], pc = J.pcols[j];
    if (i >= pr * pc) return;
    int pp = i / pc, c = i - pp * pc;
    int r = J.perm[j] ? (((pp & 3) << 7) | (pp >> 2)) : pp;
    float v = (r < J.rows[j] && c < J.cols[j]) ? J.src[j][(size_t)r * J.cols[j] + c] : 0.f;
    short h = f2bf(v);
    J.dh[j][i] = h;
    J.dl[j][i] = f2bf(v - bf2f(h));
}

// ---------------------------------------------------------------------------
// CSR build. R12: count_T also accumulates lit-row counts via atomicAdd
// (one M pass fewer; cntL pre-zeroed with hipMemsetAsync).
// ---------------------------------------------------------------------------
__global__ __launch_bounds__(256) void count_T(const float* __restrict__ M,
                                               int* __restrict__ cnt2d, int* __restrict__ cntL)
{
    int s = blockIdx.y;
    int c = blockIdx.x * 256 + threadIdx.x;
    if (c >= NC) return;
    int n = 0;
    int l0 = s * LCHUNK, l1 = l0 + LCHUNK;
    for (int l = l0; l < l1; ++l) {
        bool nz = M[(size_t)l * NC + c] != 0.f;
        n += nz ? 1 : 0;
        if (nz) atomicAdd(&cntL[l], 1);
    }
    cnt2d[(size_t)s * NC + c] = n;
}

__global__ __launch_bounds__(256) void scan_excl(const int* __restrict__ in, int* __restrict__ out, int n)
{
    const int t = threadIdx.x;
    const int per = (n + 255) >> 8;
    __shared__ int part[256];
    int s = 0;
    const int start = t * per;
    for (int i = 0; i < per; ++i) { int idx = start + i; if (idx < n) s += in[idx]; }
    part[t] = s;
    __syncthreads();
    for (int off = 1; off < 256; off <<= 1) {
        int v = (t >= off) ? part[t - off] : 0;
        __syncthreads();
        part[t] += v;
        __syncthreads();
    }
    int run = (t == 0) ? 0 : part[t - 1];
    for (int i = 0; i < per; ++i) {
        int idx = start + i;
        if (idx < n) { out[idx] = run; run += in[idx]; }
    }
    if (t == 255) out[n] = part[255];
}

__global__ __launch_bounds__(256) void fill_L(const float* __restrict__ M,
                                              const int* __restrict__ Lp, int* __restrict__ Lidx)
{
    int l = blockIdx.x, t = threadIdx.x, lane = t & 63, wid = t >> 6;
    __shared__ int wcnt[4];
    __shared__ int base;
    if (t == 0) base = Lp[l];
    __syncthreads();
    for (int c0 = 0; c0 < NC; c0 += 256) {
        int c = c0 + t;
        bool pr = (c < NC) && (M[(size_t)l * NC + c] != 0.f);
        unsigned long long m = __ballot(pr);
        if (lane == 0) wcnt[wid] = (int)__popcll(m);
        __syncthreads();
        int off = base;
        for (int w = 0; w < wid; ++w) off += wcnt[w];
        int rank = (int)__popcll(m & ((1ull << lane) - 1ull));
        if (pr) Lidx[off + rank] = c;
        __syncthreads();
        if (t == 0) base += wcnt[0] + wcnt[1] + wcnt[2] + wcnt[3];
        __syncthreads();
    }
}

__global__ __launch_bounds__(256) void colscan_T(const int* __restrict__ cnt2d,
                                                 int* __restrict__ cum2d, int* __restrict__ cntT)
{
    int c = blockIdx.x * 256 + threadIdx.x;
    if (c >= NC) return;
    int run = 0;
    for (int s = 0; s < NCHUNK; ++s) {
        cum2d[(size_t)s * NC + c] = run;
        run += cnt2d[(size_t)s * NC + c];
    }
    cntT[c] = run;
}

__global__ __launch_bounds__(256) void fill_T(const float* __restrict__ M,
                                              const int* __restrict__ Tp, const int* __restrict__ cum2d,
                                              int* __restrict__ Tidx)
{
    int s = blockIdx.y;
    int c = blockIdx.x * 256 + threadIdx.x;
    if (c >= NC) return;
    int pos = Tp[c] + cum2d[(size_t)s * NC + c];
    int l0 = s * LCHUNK, l1 = l0 + LCHUNK;
    for (int l = l0; l < l1; ++l) {
        if (M[(size_t)l * NC + c] != 0.f) Tidx[pos++] = l;
    }
}

// ---------------------------------------------------------------------------
// Vote epilogue
// ---------------------------------------------------------------------------
__global__ __launch_bounds__(256) void vote_reduce(
    const short* __restrict__ H2h, const short* __restrict__ H2l,
    const float* __restrict__ W3, const float* __restrict__ b3, float* __restrict__ accum)
{
    int wid = threadIdx.x >> 6, lane = threadIdx.x & 63;
    int r = blockIdx.x * 4 + wid;
    float s = 0.f;
    if (r < NL) {
        const short* xh = &H2h[(size_t)r * 224];
        const short* xl = &H2l[(size_t)r * 224];
        for (int k = lane; k < 200; k += 64) s += (bf2f(xh[k]) + bf2f(xl[k])) * W3[k];
    }
#pragma unroll
    for (int off = 32; off > 0; off >>= 1) s += __shfl_down(s, off);
    if (lane == 0 && r < NL) {
        float v = 1.f / (1.f + expf(-(s + b3[0])));
        atomicAdd(accum, v);
    }
}

__global__ void finalize_logit(const float* __restrict__ accum, float* __restrict__ out)
{
    float avg = accum[0] / (float)NL;
    out[0] = logf(avg / (1.f - avg));
}

// ---------------------------------------------------------------------------
// Host launcher (R11 structure; GEMMs now 1-D grids with XCD swizzle)
// ---------------------------------------------------------------------------
extern "C" void kernel_launch(void* const* d_in, const int* in_sizes, int n_in,
                              void* d_out, int out_size, void* d_ws, size_t ws_size,
                              hipStream_t stream)
{
    const float* M      = (const float*)d_in[0];
    const float* L_init = (const float*)d_in[1];
    const float* C_init = (const float*)d_in[2];
    const float* LC_W1 = (const float*)d_in[3];  const float* LC_b1 = (const float*)d_in[4];
    const float* LC_W2 = (const float*)d_in[5];  const float* LC_b2 = (const float*)d_in[6];
    const float* LC_W3 = (const float*)d_in[7];  const float* LC_b3 = (const float*)d_in[8];
    const float* CL_W1 = (const float*)d_in[9];  const float* CL_b1 = (const float*)d_in[10];
    const float* CL_W2 = (const float*)d_in[11]; const float* CL_b2 = (const float*)d_in[12];
    const float* CL_W3 = (const float*)d_in[13]; const float* CL_b3 = (const float*)d_in[14];
    const float* L_Wih = (const float*)d_in[15]; const float* L_Whh = (const float*)d_in[16];
    const float* L_b   = (const float*)d_in[17];
    const float* C_Wih = (const float*)d_in[18]; const float* C_Whh = (const float*)d_in[19];
    const float* C_b   = (const float*)d_in[20];
    const float* V_W1 = (const float*)d_in[21]; const float* V_b1 = (const float*)d_in[22];
    const float* V_W2 = (const float*)d_in[23]; const float* V_b2 = (const float*)d_in[24];
    const float* V_W3 = (const float*)d_in[25]; const float* V_b3 = (const float*)d_in[26];
    float* out = (float*)d_out;

    char* ws = (char*)d_ws;
    size_t off = 0;
    auto alloc = [&](size_t bytes) -> void* {
        void* pt = ws + off;
        off += (bytes + 255) & ~(size_t)255;
        return pt;
    };
    const size_t NE = (size_t)NRP * EMB;
    short* HAh = (short*)alloc(NE * 2); short* HAl = (short*)alloc(NE * 2);
    short* HBh = (short*)alloc(NE * 2); short* HBl = (short*)alloc(NE * 2);
    float* CA = (float*)alloc(NE * 4);  float* CB = (float*)alloc(NE * 4);
    short* msgsH = (short*)alloc(NE * 2); short* msgsL = (short*)alloc(NE * 2);
    _Float16* X = (_Float16*)alloc(NE * 2);
    short* H1h = (short*)alloc((size_t)NRP * 416 * 2); short* H1l = (short*)alloc((size_t)NRP * 416 * 2);
    short* H2h = (short*)alloc((size_t)NRP * 224 * 2); short* H2l = (short*)alloc((size_t)NRP * 224 * 2);
    float* accum = (float*)alloc(256);
    short* W1hL = (short*)alloc(512 * 128 * 2); short* W1lL = (short*)alloc(512 * 128 * 2);
    short* W1hC = (short*)alloc(512 * 128 * 2); short* W1lC = (short*)alloc(512 * 128 * 2);
    short* W2hL = (short*)alloc(256 * 416 * 2); short* W2lL = (short*)alloc(256 * 416 * 2);
    short* W2hC = (short*)alloc(256 * 416 * 2); short* W2lC = (short*)alloc(256 * 416 * 2);
    short* W3hL = (short*)alloc(128 * 224 * 2); short* W3lL = (short*)alloc(128 * 224 * 2);
    short* W3hC = (short*)alloc(128 * 224 * 2); short* W3lC = (short*)alloc(128 * 224 * 2);
    short* WihhL = (short*)alloc(512 * 128 * 2); short* WihlL = (short*)alloc(512 * 128 * 2);
    short* WhhhL = (short*)alloc(512 * 128 * 2); short* WhhlL = (short*)alloc(512 * 128 * 2);
    short* WihhC = (short*)alloc(512 * 128 * 2); short* WihlC = (short*)alloc(512 * 128 * 2);
    short* WhhhC = (short*)alloc(512 * 128 * 2); short* WhhlC = (short*)alloc(512 * 128 * 2);
    short* V1h = (short*)alloc(512 * 128 * 2); short* V1l = (short*)alloc(512 * 128 * 2);
    short* V2h = (short*)alloc(256 * 416 * 2); short* V2l = (short*)alloc(256 * 416 * 2);
    int* Lp   = (int*)alloc(4104 * 4);
    int* Tp   = (int*)alloc(8104 * 4);
    int* Lidx = (int*)alloc(1000000 * 4);
    int* Tidx = (int*)alloc(1000000 * 4);
    int* cnt2d = (int*)alloc((size_t)NCHUNK * NC * 4);
    int* cum2d = (int*)alloc((size_t)NCHUNK * NC * 4);
    int* cntL = (int*)alloc(4096 * 4);
    int* cntT = (int*)alloc(8192 * 4);
    (void)ws_size; (void)in_sizes; (void)n_in; (void)out_size;

    // --- CSR build (fused counting) ---
    hipMemsetAsync(cntL, 0, 4096 * 4, stream);
    {
        dim3 g((NC + 255) / 256, NCHUNK);
        count_T<<<g, 256, 0, stream>>>(M, cnt2d, cntL);
        colscan_T<<<(NC + 255) / 256, 256, 0, stream>>>(cnt2d, cum2d, cntT);
        scan_excl<<<1, 256, 0, stream>>>(cntT, Tp, NC);
        scan_excl<<<1, 256, 0, stream>>>(cntL, Lp, NL);
        fill_L<<<NL, 256, 0, stream>>>(M, Lp, Lidx);
        fill_T<<<g, 256, 0, stream>>>(M, Tp, cum2d, Tidx);
    }

    // --- merged weight split (1 dispatch) ---
    SplitJobs Jb{};
    auto setj = [&](int j, const float* s, short* dh, short* dl, int r, int c, int pr, int pc, int pm) {
        Jb.src[j] = s; Jb.dh[j] = dh; Jb.dl[j] = dl;
        Jb.rows[j] = r; Jb.cols[j] = c; Jb.prows[j] = pr; Jb.pcols[j] = pc; Jb.perm[j] = pm;
    };
    setj(0, LC_W1, W1hL, W1lL, 400, 128, 512, 128, 0);
    setj(1, CL_W1, W1hC, W1lC, 400, 128, 512, 128, 0);
    setj(2, LC_W2, W2hL, W2lL, 200, 400, 256, 416, 0);
    setj(3, CL_W2, W2hC, W2lC, 200, 400, 256, 416, 0);
    setj(4, LC_W3, W3hL, W3lL, 128, 200, 128, 224, 0);
    setj(5, CL_W3, W3hC, W3lC, 128, 200, 128, 224, 0);
    setj(6, L_Wih, WihhL, WihlL, 512, 128, 512, 128, 1);
    setj(7, L_Whh, WhhhL, WhhlL, 512, 128, 512, 128, 1);
    setj(8, C_Wih, WihhC, WihlC, 512, 128, 512, 128, 1);
    setj(9, C_Whh, WhhhC, WhhlC, 512, 128, 512, 128, 1);
    setj(10, V_W1, V1h, V1l, 400, 128, 512, 128, 0);
    setj(11, V_W2, V2h, V2l, 200, 400, 256, 416, 0);
    {
        dim3 g((106496 + 255) / 256, 12);
        split_all<<<g, 256, 0, stream>>>(Jb);
    }

    const int nelem_blocks = (int)((NE + 255) / 256);
    init_states<<<nelem_blocks, 256, 0, stream>>>(L_init, C_init, HAh, HAl, CA, msgsH, msgsL, accum);

    // --- 30 message-passing steps (5 kernels each; 1-D swizzled grids) ---
    short *Hch = HAh, *Hcl = HAl, *Hnh = HBh, *Hnl = HBl;
    float *Ccur = CA, *Cnxt = CB;
    for (int step = 0; step < TSTEPS; ++step) {
        gemm64<128, 1, false, true><<<7 * 192, 256, 0, stream>>>(
            Hch, Hcl, nullptr, nullptr,
            W1hL, W1lL, W1hC, W1lC, nullptr, nullptr, nullptr, nullptr,
            LC_b1, CL_b1, H1h, H1l, nullptr, nullptr, nullptr, 400, 416, 7);
        gemm64<416, 1, false, true><<<4 * 192, 256, 0, stream>>>(
            H1h, H1l, nullptr, nullptr,
            W2hL, W2lL, W2hC, W2lC, nullptr, nullptr, nullptr, nullptr,
            LC_b2, CL_b2, H2h, H2l, nullptr, nullptr, nullptr, 200, 224, 4);
        gemm64<224, 4, false, false><<<2 * 192, 256, 0, stream>>>(
            H2h, H2l, nullptr, nullptr,
            W3hL, W3lL, W3hC, W3lC, nullptr, nullptr, nullptr, nullptr,
            LC_b3, CL_b3, nullptr, nullptr, (float*)X, nullptr, nullptr, 128, 128, 2);
        spmm_kernel<<<(NRREAL + 3) / 4, 256, 0, stream>>>(Lp, Lidx, Tp, Tidx, X, msgsH, msgsL);
        gemm64<128, 3, true, false><<<8 * 192, 256, 0, stream>>>(
            msgsH, msgsL, Hch, Hcl,
            WihhL, WihlL, WihhC, WihlC, WhhhL, WhhlL, WhhhC, WhhlC,
            L_b, C_b, Hnh, Hnl, nullptr, Ccur, Cnxt, 512, 512, 8);
        short* th = Hch; Hch = Hnh; Hnh = th;
        short* tl = Hcl; Hcl = Hnl; Hnl = tl;
        float* tc = Ccur; Ccur = Cnxt; Cnxt = tc;
    }

    // --- vote MLP + logit (lit rows only: 64 row panels of 64) ---
    gemm64<128, 1, false, true><<<7 * 64, 256, 0, stream>>>(
        Hch, Hcl, nullptr, nullptr,
        V1h, V1l, V1h, V1l, nullptr, nullptr, nullptr, nullptr,
        V_b1, V_b1, H1h, H1l, nullptr, nullptr, nullptr, 400, 416, 7);
    gemm64<416, 1, false, true><<<4 * 64, 256, 0, stream>>>(
        H1h, H1l, nullptr, nullptr,
        V2h, V2l, V2h, V2l, nullptr, nullptr, nullptr, nullptr,
        V_b2, V_b2, H2h, H2l, nullptr, nullptr, nullptr, 200, 224, 4);
    vote_reduce<<<(NL + 3) / 4, 256, 0, stream>>>(H2h, H2l, V_W3, V_b3, accum);
    finalize_logit<<<1, 1, 0, stream>>>(accum, out);
}

// Round 14
// 3007.950 us; speedup vs baseline: 6.0010x; 1.0161x over previous
//
#include <hip/hip_runtime.h>

#define NL 4000
#define NC 8000
#define EMB 128
#define ROWC0 4096           // clause region start (64-aligned)
#define NRP 12288            // padded total rows (192 x 64)
#define NRREAL (ROWC0 + NC)  // 12096 rows with data
#define TSTEPS 30
#define LCHUNK 80
#define NCHUNK 50

typedef __attribute__((ext_vector_type(8))) short bf16x8;
typedef __attribute__((ext_vector_type(4))) float f32x4;

__device__ __forceinline__ short f2bf(float x) {
    union { float f; unsigned u; } v; v.f = x;
    unsigned r = v.u + 0x7fffu + ((v.u >> 16) & 1u);
    return (short)(r >> 16);
}
__device__ __forceinline__ float bf2f(short s) {
    union { unsigned u; float f; } v; v.u = ((unsigned)(unsigned short)s) << 16;
    return v.f;
}
__device__ __forceinline__ float sigf(float x) { return 1.f / (1.f + expf(-x)); }
__device__ __forceinline__ float2 h2f2(unsigned u) {
    union { unsigned v; _Float16 h[2]; } x; x.v = u;
    return make_float2((float)x.h[0], (float)x.h[1]);
}
__device__ __forceinline__ void gload16(const void* g, void* l) {
    __builtin_amdgcn_global_load_lds(
        (const __attribute__((address_space(1))) unsigned int*)g,
        (__attribute__((address_space(3))) unsigned int*)l, 16, 0, 0);
}

// ---------------------------------------------------------------------------
// Split-bf16 MFMA GEMM (R12-verified, measured best): 64x64 tile, 256 thr
// (4 waves 2x2, wave 32x32). Single-buffer 128-K mega-chunk staging, XCD-
// chunked bijective swizzle (grid % 8 == 0 on all launches).
// product = Ah*Wh + Ah*Wl + Al*Wh in fp32 acc.
// OUTM: 1 = split-bf16 out (+relu), 4 = fp16 out, 3 = fused LSTM epilogue.
// ---------------------------------------------------------------------------
template<int KS, int OUTM, bool TWOA, bool RELU>
__global__ __launch_bounds__(256) void gemm64(
    const short* __restrict__ A1h, const short* __restrict__ A1l,
    const short* __restrict__ A2h, const short* __restrict__ A2l,
    const short* __restrict__ B1hL, const short* __restrict__ B1lL,
    const short* __restrict__ B1hC, const short* __restrict__ B1lC,
    const short* __restrict__ B2hL, const short* __restrict__ B2lL,
    const short* __restrict__ B2hC, const short* __restrict__ B2lC,
    const float* __restrict__ biasL, const float* __restrict__ biasC,
    short* __restrict__ OH, short* __restrict__ OL, float* __restrict__ OF,
    const float* __restrict__ Cold, float* __restrict__ Cnew,
    int Freal, int Fstore, int nx)
{
    __shared__ short sAh[4 * 2048];   // [chunk32 q][row 64][32] per split
    __shared__ short sAl[4 * 2048];
    __shared__ short sBh[4 * 2048];
    __shared__ short sBl[4 * 2048];

    const int flat = blockIdx.x;
    const int qx = (int)gridDim.x >> 3;
    const int wg = (flat & 7) * qx + (flat >> 3);
    const int row0 = (wg / nx) * 64;
    const int c0 = (wg % nx) * 64;
    const bool isC = (row0 >= ROWC0);
    const int t = threadIdx.x;
    const int lane = t & 63;
    const int w = t >> 6;
    const int wr = w >> 1, wc = w & 1;
    const int l15 = lane & 15;

    f32x4 acc[2][2] = {};
    bool first = true;

    const int nph = TWOA ? 2 : 1;
    for (int ph = 0; ph < nph; ++ph) {
        const short* Ah = (TWOA && ph) ? A2h : A1h;
        const short* Al = (TWOA && ph) ? A2l : A1l;
        const short* Bh = (TWOA && ph) ? (isC ? B2hC : B2hL) : (isC ? B1hC : B1hL);
        const short* Bl = (TWOA && ph) ? (isC ? B2lC : B2lL) : (isC ? B1lC : B1lL);

        for (int kc0 = 0; kc0 < KS; kc0 += 128) {
            const int n32 = ((KS - kc0) >> 5) < 4 ? ((KS - kc0) >> 5) : 4;
            if (!first) __syncthreads();   // buffer free (prev chunk consumed)
            first = false;
            const int row = t >> 2, slot = t & 3;
#pragma unroll 4
            for (int q = 0; q < n32; ++q) {
                int gk = kc0 + q * 32 + ((slot ^ ((row >> 1) & 3)) << 3);
                size_t ga = (size_t)(row0 + row) * KS + gk;
                size_t gb = (size_t)(c0 + row) * KS + gk;
                gload16(Ah + ga, &sAh[q * 2048 + t * 8]);
                gload16(Al + ga, &sAl[q * 2048 + t * 8]);
                gload16(Bh + gb, &sBh[q * 2048 + t * 8]);
                gload16(Bl + gb, &sBl[q * 2048 + t * 8]);
            }
            asm volatile("s_waitcnt vmcnt(0)" ::: "memory");
            __syncthreads();
#pragma unroll 4
            for (int q = 0; q < n32; ++q) {
                bf16x8 af[2][2], bf[2][2];
#pragma unroll
                for (int s = 0; s < 2; ++s) {
                    int ar = wr * 32 + s * 16 + l15;
                    int aslot = (lane >> 4) ^ ((ar >> 1) & 3);
                    int ai = q * 2048 + ar * 32 + aslot * 8;
                    af[s][0] = *(const bf16x8*)&sAh[ai];
                    af[s][1] = *(const bf16x8*)&sAl[ai];
                    int br = wc * 32 + s * 16 + l15;
                    int bslot = (lane >> 4) ^ ((br >> 1) & 3);
                    int bi = q * 2048 + br * 32 + bslot * 8;
                    bf[s][0] = *(const bf16x8*)&sBh[bi];
                    bf[s][1] = *(const bf16x8*)&sBl[bi];
                }
#pragma unroll
                for (int s = 0; s < 2; ++s)
#pragma unroll
                    for (int u = 0; u < 2; ++u) {
                        acc[s][u] = __builtin_amdgcn_mfma_f32_16x16x32_bf16(af[s][0], bf[u][0], acc[s][u], 0, 0, 0);
                        acc[s][u] = __builtin_amdgcn_mfma_f32_16x16x32_bf16(af[s][0], bf[u][1], acc[s][u], 0, 0, 0);
                        acc[s][u] = __builtin_amdgcn_mfma_f32_16x16x32_bf16(af[s][1], bf[u][0], acc[s][u], 0, 0, 0);
                    }
            }
        }
    }

    if (OUTM != 3) {
        // C/D frag layout: col = lane&15, row = (lane>>4)*4 + reg (m89)
#pragma unroll
        for (int u = 0; u < 2; ++u) {
            int col = c0 + wc * 32 + u * 16 + l15;
            if (col >= Fstore) continue;
            float bv = (col < Freal) ? (isC ? biasC[col] : biasL[col]) : 0.f;
#pragma unroll
            for (int s = 0; s < 2; ++s)
#pragma unroll
                for (int j = 0; j < 4; ++j) {
                    int rowo = row0 + wr * 32 + s * 16 + (lane >> 4) * 4 + j;
                    float v = acc[s][u][j] + bv;
                    if (RELU) v = fmaxf(v, 0.f);
                    size_t oi = (size_t)rowo * Fstore + col;
                    if (OUTM == 1) {
                        short h = f2bf(v);
                        OH[oi] = h;
                        OL[oi] = f2bf(v - bf2f(h));
                    } else {
                        ((_Float16*)OF)[oi] = (_Float16)v;
                    }
                }
        }
    } else {
        // Fused LSTM epilogue (R5-R12 verified). colp = permuted gate col 4j+g.
        const int ql = lane & 3;
#pragma unroll
        for (int u = 0; u < 2; ++u) {
            int colp = c0 + wc * 32 + u * 16 + l15;
            int wrr = (colp & 3) * 128 + (colp >> 2);
            float bv = isC ? biasC[wrr] : biasL[wrr];
            int j = colp >> 2;
#pragma unroll
            for (int s = 0; s < 2; ++s) {
                float ii = 0.f, ff = 0.f, gg = 0.f, oo = 0.f;
#pragma unroll
                for (int r2 = 0; r2 < 4; ++r2) {
                    float v0 = acc[s][u][r2] + bv;
                    float x1 = __shfl_xor(v0, 1);
                    float x2 = __shfl_xor(v0, 2);
                    float x3 = __shfl_xor(v0, 3);
                    float iv = (ql == 0) ? v0 : (ql == 1) ? x1 : (ql == 2) ? x2 : x3;
                    float fv = (ql == 0) ? x1 : (ql == 1) ? v0 : (ql == 2) ? x3 : x2;
                    float gv = (ql == 0) ? x2 : (ql == 1) ? x3 : (ql == 2) ? v0 : x1;
                    float ov = (ql == 0) ? x3 : (ql == 1) ? x2 : (ql == 2) ? x1 : v0;
                    if (ql == r2) { ii = iv; ff = fv; gg = gv; oo = ov; }
                }
                int rowo = row0 + wr * 32 + s * 16 + (lane >> 4) * 4 + ql;
                size_t ci = (size_t)rowo * 128 + j;
                float c2 = sigf(ff) * Cold[ci] + sigf(ii) * tanhf(gg);
                float h2 = sigf(oo) * tanhf(c2);
                Cnew[ci] = c2;
                short h = f2bf(h2);
                OH[ci] = h;
                OL[ci] = f2bf(h2 - bf2f(h));
            }
        }
    }
}

// ---------------------------------------------------------------------------
// SpMM gather (R12-verified): 4-edge-parallel, dwordx4, shfl fold.
// ---------------------------------------------------------------------------
__global__ __launch_bounds__(256) void spmm_kernel(
    const int* __restrict__ Lp, const int* __restrict__ Li,
    const int* __restrict__ Tp, const int* __restrict__ Ti,
    const _Float16* __restrict__ X, short* __restrict__ mh, short* __restrict__ ml)
{
    const int r = blockIdx.x * 4 + (threadIdx.x >> 6);
    const int lane = threadIdx.x & 63;
    const int eg = lane >> 4;
    const int cl = lane & 15;
    if (r >= NRREAL) return;
    const int cp = cl * 8;

    int b, e, base;
    const int* idx;
    if (r < NL) { b = Lp[r]; e = Lp[r + 1]; idx = Li; base = ROWC0; }
    else if (r >= ROWC0) { int c = r - ROWC0; b = Tp[c]; e = Tp[c + 1]; idx = Ti; base = 0; }
    else return;

    float s0 = 0.f, s1 = 0.f, s2 = 0.f, s3 = 0.f, s4 = 0.f, s5 = 0.f, s6 = 0.f, s7 = 0.f;
    int i = b + eg;
    bool has = i < e;
    uint4 v = make_uint4(0, 0, 0, 0);
    if (has) v = *(const uint4*)&X[(size_t)(base + idx[i]) * EMB + cp];
    while (has) {
        int in_ = i + 4;
        bool hn = in_ < e;
        uint4 vn = v;
        if (hn) vn = *(const uint4*)&X[(size_t)(base + idx[in_]) * EMB + cp];
        float2 f0 = h2f2(v.x), f1 = h2f2(v.y), f2 = h2f2(v.z), f3 = h2f2(v.w);
        s0 += f0.x; s1 += f0.y; s2 += f1.x; s3 += f1.y;
        s4 += f2.x; s5 += f2.y; s6 += f3.x; s7 += f3.y;
        v = vn; i = in_; has = hn;
    }
    s0 += __shfl_xor(s0, 16); s0 += __shfl_xor(s0, 32);
    s1 += __shfl_xor(s1, 16); s1 += __shfl_xor(s1, 32);
    s2 += __shfl_xor(s2, 16); s2 += __shfl_xor(s2, 32);
    s3 += __shfl_xor(s3, 16); s3 += __shfl_xor(s3, 32);
    s4 += __shfl_xor(s4, 16); s4 += __shfl_xor(s4, 32);
    s5 += __shfl_xor(s5, 16); s5 += __shfl_xor(s5, 32);
    s6 += __shfl_xor(s6, 16); s6 += __shfl_xor(s6, 32);
    s7 += __shfl_xor(s7, 16); s7 += __shfl_xor(s7, 32);

    if (eg == 0) {
        float sv[8] = { s0, s1, s2, s3, s4, s5, s6, s7 };
        unsigned hp[4], lp[4];
#pragma unroll
        for (int j = 0; j < 4; ++j) {
            short ha = f2bf(sv[2 * j]), hb = f2bf(sv[2 * j + 1]);
            hp[j] = (unsigned)(unsigned short)ha | ((unsigned)(unsigned short)hb << 16);
            short la = f2bf(sv[2 * j] - bf2f(ha)), lb = f2bf(sv[2 * j + 1] - bf2f(hb));
            lp[j] = (unsigned)(unsigned short)la | ((unsigned)(unsigned short)lb << 16);
        }
        size_t oi = (size_t)r * EMB + cp;
        *(uint4*)&mh[oi] = make_uint4(hp[0], hp[1], hp[2], hp[3]);
        *(uint4*)&ml[oi] = make_uint4(lp[0], lp[1], lp[2], lp[3]);
    }
}

__global__ __launch_bounds__(256) void init_states(
    const float* __restrict__ Li, const float* __restrict__ Ci,
    short* __restrict__ Hh, short* __restrict__ Hl, float* __restrict__ C,
    short* __restrict__ msgsH, short* __restrict__ msgsL, float* __restrict__ accum)
{
    size_t idx = (size_t)blockIdx.x * 256 + threadIdx.x;
    if (idx >= (size_t)NRP * EMB) return;
    int r = (int)(idx >> 7);
    int e = (int)(idx & 127);
    float h = 0.f;
    if (r < NL) h = Li[e];
    else if (r >= ROWC0 && r < NRREAL) h = Ci[e];
    short hh = f2bf(h);
    Hh[idx] = hh;
    Hl[idx] = f2bf(h - bf2f(hh));
    C[idx] = 0.f;
    if (r >= NRREAL || (r >= NL && r < ROWC0)) { msgsH[idx] = 0; msgsL[idx] = 0; }
    if (idx == 0) accum[0] = 0.f;
}

// ---------------------------------------------------------------------------
// Merged weight split (1 dispatch; verified). perm = LSTM gate permutation.
// ---------------------------------------------------------------------------
struct SplitJobs {
    const float* src[12];
    short* dh[12]; short* dl[12];
    int rows[12], cols[12], prows[12], pcols[12], perm[12];
};

__global__ __launch_bounds__(256) void split_all(SplitJobs J)
{
    int j = blockIdx.y;
    int i = blockIdx.x * 256 + threadIdx.x;
    int pr = J.prows[j], pc = J.pcols[j];
    if (i >= pr * pc) return;
    int pp = i / pc, c = i - pp * pc;
    int r = J.perm[j] ? (((pp & 3) << 7) | (pp >> 2)) : pp;
    float v = (r < J.rows[j] && c < J.cols[j]) ? J.src[j][(size_t)r * J.cols[j] + c] : 0.f;
    short h = f2bf(v);
    J.dh[j][i] = h;
    J.dl[j][i] = f2bf(v - bf2f(h));
}

// ---------------------------------------------------------------------------
// CSR build (R14: float4-vectorized counts/fills, no atomics — the
// precision-neutral part of R13)
// ---------------------------------------------------------------------------
__global__ __launch_bounds__(256) void count_rows_L(const float* __restrict__ M, int* __restrict__ cnt)
{
    int l = blockIdx.x, t = threadIdx.x;
    int n = 0;
    for (int c4 = t; c4 < NC / 4; c4 += 256) {
        float4 v = *(const float4*)&M[(size_t)l * NC + c4 * 4];
        n += (v.x != 0.f) + (v.y != 0.f) + (v.z != 0.f) + (v.w != 0.f);
    }
#pragma unroll
    for (int off = 32; off > 0; off >>= 1) n += __shfl_down(n, off);
    __shared__ int wsum[4];
    if ((t & 63) == 0) wsum[t >> 6] = n;
    __syncthreads();
    if (t == 0) cnt[l] = wsum[0] + wsum[1] + wsum[2] + wsum[3];
}

__global__ __launch_bounds__(256) void count_T(const float* __restrict__ M, int* __restrict__ cnt2d)
{
    int s = blockIdx.y;
    int c4 = blockIdx.x * 256 + threadIdx.x;
    if (c4 >= NC / 4) return;
    int n0 = 0, n1 = 0, n2 = 0, n3 = 0;
    int l0 = s * LCHUNK, l1 = l0 + LCHUNK;
    for (int l = l0; l < l1; ++l) {
        float4 v = *(const float4*)&M[(size_t)l * NC + c4 * 4];
        n0 += v.x != 0.f; n1 += v.y != 0.f; n2 += v.z != 0.f; n3 += v.w != 0.f;
    }
    size_t o = (size_t)s * NC + c4 * 4;
    cnt2d[o] = n0; cnt2d[o + 1] = n1; cnt2d[o + 2] = n2; cnt2d[o + 3] = n3;
}

__global__ __launch_bounds__(256) void scan_excl(const int* __restrict__ in, int* __restrict__ out, int n)
{
    const int t = threadIdx.x;
    const int per = (n + 255) >> 8;
    __shared__ int part[256];
    int s = 0;
    const int start = t * per;
    for (int i = 0; i < per; ++i) { int idx = start + i; if (idx < n) s += in[idx]; }
    part[t] = s;
    __syncthreads();
    for (int off = 1; off < 256; off <<= 1) {
        int v = (t >= off) ? part[t - off] : 0;
        __syncthreads();
        part[t] += v;
        __syncthreads();
    }
    int run = (t == 0) ? 0 : part[t - 1];
    for (int i = 0; i < per; ++i) {
        int idx = start + i;
        if (idx < n) { out[idx] = run; run += in[idx]; }
    }
    if (t == 255) out[n] = part[255];
}

__global__ __launch_bounds__(256) void fill_L(const float* __restrict__ M,
                                              const int* __restrict__ Lp, int* __restrict__ Lidx)
{
    int l = blockIdx.x, t = threadIdx.x, lane = t & 63, wid = t >> 6;
    __shared__ int wcnt[4];
    __shared__ int base;
    if (t == 0) base = Lp[l];
    __syncthreads();
    for (int c0 = 0; c0 < NC; c0 += 256) {
        int c = c0 + t;
        bool pr = (c < NC) && (M[(size_t)l * NC + c] != 0.f);
        unsigned long long m = __ballot(pr);
        if (lane == 0) wcnt[wid] = (int)__popcll(m);
        __syncthreads();
        int off = base;
        for (int w = 0; w < wid; ++w) off += wcnt[w];
        int rank = (int)__popcll(m & ((1ull << lane) - 1ull));
        if (pr) Lidx[off + rank] = c;
        __syncthreads();
        if (t == 0) base += wcnt[0] + wcnt[1] + wcnt[2] + wcnt[3];
        __syncthreads();
    }
}

__global__ __launch_bounds__(256) void colscan_T(const int* __restrict__ cnt2d,
                                                 int* __restrict__ cum2d, int* __restrict__ cntT)
{
    int c = blockIdx.x * 256 + threadIdx.x;
    if (c >= NC) return;
    int run = 0;
    for (int s = 0; s < NCHUNK; ++s) {
        cum2d[(size_t)s * NC + c] = run;
        run += cnt2d[(size_t)s * NC + c];
    }
    cntT[c] = run;
}

__global__ __launch_bounds__(256) void fill_T(const float* __restrict__ M,
                                              const int* __restrict__ Tp, const int* __restrict__ cum2d,
                                              int* __restrict__ Tidx)
{
    int s = blockIdx.y;
    int c4 = blockIdx.x * 256 + threadIdx.x;
    if (c4 >= NC / 4) return;
    int c = c4 * 4;
    int p0 = Tp[c] + cum2d[(size_t)s * NC + c];
    int p1 = Tp[c + 1] + cum2d[(size_t)s * NC + c + 1];
    int p2 = Tp[c + 2] + cum2d[(size_t)s * NC + c + 2];
    int p3 = Tp[c + 3] + cum2d[(size_t)s * NC + c + 3];
    int l0 = s * LCHUNK, l1 = l0 + LCHUNK;
    for (int l = l0; l < l1; ++l) {
        float4 v = *(const float4*)&M[(size_t)l * NC + c];
        if (v.x != 0.f) Tidx[p0++] = l;
        if (v.y != 0.f) Tidx[p1++] = l;
        if (v.z != 0.f) Tidx[p2++] = l;
        if (v.w != 0.f) Tidx[p3++] = l;
    }
}

// ---------------------------------------------------------------------------
// Vote epilogue
// ---------------------------------------------------------------------------
__global__ __launch_bounds__(256) void vote_reduce(
    const short* __restrict__ H2h, const short* __restrict__ H2l,
    const float* __restrict__ W3, const float* __restrict__ b3, float* __restrict__ accum)
{
    int wid = threadIdx.x >> 6, lane = threadIdx.x & 63;
    int r = blockIdx.x * 4 + wid;
    float s = 0.f;
    if (r < NL) {
        const short* xh = &H2h[(size_t)r * 224];
        const short* xl = &H2l[(size_t)r * 224];
        for (int k = lane; k < 200; k += 64) s += (bf2f(xh[k]) + bf2f(xl[k])) * W3[k];
    }
#pragma unroll
    for (int off = 32; off > 0; off >>= 1) s += __shfl_down(s, off);
    if (lane == 0 && r < NL) {
        float v = 1.f / (1.f + expf(-(s + b3[0])));
        atomicAdd(accum, v);
    }
}

__global__ void finalize_logit(const float* __restrict__ accum, float* __restrict__ out)
{
    float avg = accum[0] / (float)NL;
    out[0] = logf(avg / (1.f - avg));
}

// ---------------------------------------------------------------------------
// Host launcher (R12 structure)
// ---------------------------------------------------------------------------
extern "C" void kernel_launch(void* const* d_in, const int* in_sizes, int n_in,
                              void* d_out, int out_size, void* d_ws, size_t ws_size,
                              hipStream_t stream)
{
    const float* M      = (const float*)d_in[0];
    const float* L_init = (const float*)d_in[1];
    const float* C_init = (const float*)d_in[2];
    const float* LC_W1 = (const float*)d_in[3];  const float* LC_b1 = (const float*)d_in[4];
    const float* LC_W2 = (const float*)d_in[5];  const float* LC_b2 = (const float*)d_in[6];
    const float* LC_W3 = (const float*)d_in[7];  const float* LC_b3 = (const float*)d_in[8];
    const float* CL_W1 = (const float*)d_in[9];  const float* CL_b1 = (const float*)d_in[10];
    const float* CL_W2 = (const float*)d_in[11]; const float* CL_b2 = (const float*)d_in[12];
    const float* CL_W3 = (const float*)d_in[13]; const float* CL_b3 = (const float*)d_in[14];
    const float* L_Wih = (const float*)d_in[15]; const float* L_Whh = (const float*)d_in[16];
    const float* L_b   = (const float*)d_in[17];
    const float* C_Wih = (const float*)d_in[18]; const float* C_Whh = (const float*)d_in[19];
    const float* C_b   = (const float*)d_in[20];
    const float* V_W1 = (const float*)d_in[21]; const float* V_b1 = (const float*)d_in[22];
    const float* V_W2 = (const float*)d_in[23]; const float* V_b2 = (const float*)d_in[24];
    const float* V_W3 = (const float*)d_in[25]; const float* V_b3 = (const float*)d_in[26];
    float* out = (float*)d_out;

    char* ws = (char*)d_ws;
    size_t off = 0;
    auto alloc = [&](size_t bytes) -> void* {
        void* pt = ws + off;
        off += (bytes + 255) & ~(size_t)255;
        return pt;
    };
    const size_t NE = (size_t)NRP * EMB;
    short* HAh = (short*)alloc(NE * 2); short* HAl = (short*)alloc(NE * 2);
    short* HBh = (short*)alloc(NE * 2); short* HBl = (short*)alloc(NE * 2);
    float* CA = (float*)alloc(NE * 4);  float* CB = (float*)alloc(NE * 4);
    short* msgsH = (short*)alloc(NE * 2); short* msgsL = (short*)alloc(NE * 2);
    _Float16* X = (_Float16*)alloc(NE * 2);
    short* H1h = (short*)alloc((size_t)NRP * 416 * 2); short* H1l = (short*)alloc((size_t)NRP * 416 * 2);
    short* H2h = (short*)alloc((size_t)NRP * 224 * 2); short* H2l = (short*)alloc((size_t)NRP * 224 * 2);
    float* accum = (float*)alloc(256);
    short* W1hL = (short*)alloc(512 * 128 * 2); short* W1lL = (short*)alloc(512 * 128 * 2);
    short* W1hC = (short*)alloc(512 * 128 * 2); short* W1lC = (short*)alloc(512 * 128 * 2);
    short* W2hL = (short*)alloc(256 * 416 * 2); short* W2lL = (short*)alloc(256 * 416 * 2);
    short* W2hC = (short*)alloc(256 * 416 * 2); short* W2lC = (short*)alloc(256 * 416 * 2);
    short* W3hL = (short*)alloc(128 * 224 * 2); short* W3lL = (short*)alloc(128 * 224 * 2);
    short* W3hC = (short*)alloc(128 * 224 * 2); short* W3lC = (short*)alloc(128 * 224 * 2);
    short* WihhL = (short*)alloc(512 * 128 * 2); short* WihlL = (short*)alloc(512 * 128 * 2);
    short* WhhhL = (short*)alloc(512 * 128 * 2); short* WhhlL = (short*)alloc(512 * 128 * 2);
    short* WihhC = (short*)alloc(512 * 128 * 2); short* WihlC = (short*)alloc(512 * 128 * 2);
    short* WhhhC = (short*)alloc(512 * 128 * 2); short* WhhlC = (short*)alloc(512 * 128 * 2);
    short* V1h = (short*)alloc(512 * 128 * 2); short* V1l = (short*)alloc(512 * 128 * 2);
    short* V2h = (short*)alloc(256 * 416 * 2); short* V2l = (short*)alloc(256 * 416 * 2);
    int* Lp   = (int*)alloc(4104 * 4);
    int* Tp   = (int*)alloc(8104 * 4);
    int* Lidx = (int*)alloc(1000000 * 4);
    int* Tidx = (int*)alloc(1000000 * 4);
    int* cnt2d = (int*)alloc((size_t)NCHUNK * NC * 4);
    int* cum2d = (int*)alloc((size_t)NCHUNK * NC * 4);
    int* cntL = (int*)alloc(4096 * 4);
    int* cntT = (int*)alloc(8192 * 4);
    (void)ws_size; (void)in_sizes; (void)n_in; (void)out_size;

    // --- CSR build (vectorized) ---
    count_rows_L<<<NL, 256, 0, stream>>>(M, cntL);
    {
        dim3 g((NC / 4 + 255) / 256, NCHUNK);
        count_T<<<g, 256, 0, stream>>>(M, cnt2d);
        colscan_T<<<(NC + 255) / 256, 256, 0, stream>>>(cnt2d, cum2d, cntT);
        scan_excl<<<1, 256, 0, stream>>>(cntT, Tp, NC);
        scan_excl<<<1, 256, 0, stream>>>(cntL, Lp, NL);
        fill_L<<<NL, 256, 0, stream>>>(M, Lp, Lidx);
        fill_T<<<g, 256, 0, stream>>>(M, Tp, cum2d, Tidx);
    }

    // --- merged weight split (1 dispatch) ---
    SplitJobs Jb{};
    auto setj = [&](int j, const float* s, short* dh, short* dl, int r, int c, int pr, int pc, int pm) {
        Jb.src[j] = s; Jb.dh[j] = dh; Jb.dl[j] = dl;
        Jb.rows[j] = r; Jb.cols[j] = c; Jb.prows[j] = pr; Jb.pcols[j] = pc; Jb.perm[j] = pm;
    };
    setj(0, LC_W1, W1hL, W1lL, 400, 128, 512, 128, 0);
    setj(1, CL_W1, W1hC, W1lC, 400, 128, 512, 128, 0);
    setj(2, LC_W2, W2hL, W2lL, 200, 400, 256, 416, 0);
    setj(3, CL_W2, W2hC, W2lC, 200, 400, 256, 416, 0);
    setj(4, LC_W3, W3hL, W3lL, 128, 200, 128, 224, 0);
    setj(5, CL_W3, W3hC, W3lC, 128, 200, 128, 224, 0);
    setj(6, L_Wih, WihhL, WihlL, 512, 128, 512, 128, 1);
    setj(7, L_Whh, WhhhL, WhhlL, 512, 128, 512, 128, 1);
    setj(8, C_Wih, WihhC, WihlC, 512, 128, 512, 128, 1);
    setj(9, C_Whh, WhhhC, WhhlC, 512, 128, 512, 128, 1);
    setj(10, V_W1, V1h, V1l, 400, 128, 512, 128, 0);
    setj(11, V_W2, V2h, V2l, 200, 400, 256, 416, 0);
    {
        dim3 g((106496 + 255) / 256, 12);
        split_all<<<g, 256, 0, stream>>>(Jb);
    }

    const int nelem_blocks = (int)((NE + 255) / 256);
    init_states<<<nelem_blocks, 256, 0, stream>>>(L_init, C_init, HAh, HAl, CA, msgsH, msgsL, accum);

    // --- 30 message-passing steps (5 kernels each; 1-D swizzled grids) ---
    short *Hch = HAh, *Hcl = HAl, *Hnh = HBh, *Hnl = HBl;
    float *Ccur = CA, *Cnxt = CB;
    for (int step = 0; step < TSTEPS; ++step) {
        gemm64<128, 1, false, true><<<7 * 192, 256, 0, stream>>>(
            Hch, Hcl, nullptr, nullptr,
            W1hL, W1lL, W1hC, W1lC, nullptr, nullptr, nullptr, nullptr,
            LC_b1, CL_b1, H1h, H1l, nullptr, nullptr, nullptr, 400, 416, 7);
        gemm64<416, 1, false, true><<<4 * 192, 256, 0, stream>>>(
            H1h, H1l, nullptr, nullptr,
            W2hL, W2lL, W2hC, W2lC, nullptr, nullptr, nullptr, nullptr,
            LC_b2, CL_b2, H2h, H2l, nullptr, nullptr, nullptr, 200, 224, 4);
        gemm64<224, 4, false, false><<<2 * 192, 256, 0, stream>>>(
            H2h, H2l, nullptr, nullptr,
            W3hL, W3lL, W3hC, W3lC, nullptr, nullptr, nullptr, nullptr,
            LC_b3, CL_b3, nullptr, nullptr, (float*)X, nullptr, nullptr, 128, 128, 2);
        spmm_kernel<<<(NRREAL + 3) / 4, 256, 0, stream>>>(Lp, Lidx, Tp, Tidx, X, msgsH, msgsL);
        gemm64<128, 3, true, false><<<8 * 192, 256, 0, stream>>>(
            msgsH, msgsL, Hch, Hcl,
            WihhL, WihlL, WihhC, WihlC, WhhhL, WhhlL, WhhhC, WhhlC,
            L_b, C_b, Hnh, Hnl, nullptr, Ccur, Cnxt, 512, 512, 8);
        short* th = Hch; Hch = Hnh; Hnh = th;
        short* tl = Hcl; Hcl = Hnl; Hnl = tl;
        float* tc = Ccur; Ccur = Cnxt; Cnxt = tc;
    }

    // --- vote MLP + logit (lit rows only: 64 row panels of 64) ---
    gemm64<128, 1, false, true><<<7 * 64, 256, 0, stream>>>(
        Hch, Hcl, nullptr, nullptr,
        V1h, V1l, V1h, V1l, nullptr, nullptr, nullptr, nullptr,
        V_b1, V_b1, H1h, H1l, nullptr, nullptr, nullptr, 400, 416, 7);
    gemm64<416, 1, false, true><<<4 * 64, 256, 0, stream>>>(
        H1h, H1l, nullptr, nullptr,
        V2h, V2l, V2h, V2l, nullptr, nullptr, nullptr, nullptr,
        V_b2, V_b2, H2h, H2l, nullptr, nullptr, nullptr, 200, 224, 4);
    vote_reduce<<<(NL + 3) / 4, 256, 0, stream>>>(H2h, H2l, V_W3, V_b3, accum);
    finalize_logit<<<1, 1, 0, stream>>>(accum, out);
}

// Round 15
// 2978.137 us; speedup vs baseline: 6.0611x; 1.0100x over previous
//
#include <hip/hip_runtime.h>

#define NL 4000
#define NC 8000
#define EMB 128
#define ROWC0 4096           // clause region start (64-aligned)
#define NRP 12288            // padded total rows (192 x 64)
#define NRREAL (ROWC0 + NC)  // 12096 rows with data
#define TSTEPS 30
#define LCHUNK 80
#define NCHUNK 50

typedef __attribute__((ext_vector_type(8))) short bf16x8;
typedef __attribute__((ext_vector_type(4))) float f32x4;

__device__ __forceinline__ short f2bf(float x) {
    union { float f; unsigned u; } v; v.f = x;
    unsigned r = v.u + 0x7fffu + ((v.u >> 16) & 1u);
    return (short)(r >> 16);
}
__device__ __forceinline__ float bf2f(short s) {
    union { unsigned u; float f; } v; v.u = ((unsigned)(unsigned short)s) << 16;
    return v.f;
}
__device__ __forceinline__ float sigf(float x) { return 1.f / (1.f + expf(-x)); }
__device__ __forceinline__ float2 h2f2(unsigned u) {
    union { unsigned v; _Float16 h[2]; } x; x.v = u;
    return make_float2((float)x.h[0], (float)x.h[1]);
}
__device__ __forceinline__ void gload16(const void* g, void* l) {
    __builtin_amdgcn_global_load_lds(
        (const __attribute__((address_space(1))) unsigned int*)g,
        (__attribute__((address_space(3))) unsigned int*)l, 16, 0, 0);
}

// ---------------------------------------------------------------------------
// Split-bf16 MFMA GEMM (R12/R14-verified, measured best): 64x64 tile, 256 thr
// (4 waves 2x2, wave 32x32). Single-buffer 128-K mega-chunk staging, XCD-
// chunked bijective swizzle (grid % 8 == 0 on all launches).
// product = Ah*Wh + Ah*Wl + Al*Wh in fp32 acc.
// OUTM: 1 = split-bf16 out (+relu), 4 = fp16 out, 3 = fused LSTM epilogue.
// ---------------------------------------------------------------------------
template<int KS, int OUTM, bool TWOA, bool RELU>
__global__ __launch_bounds__(256) void gemm64(
    const short* __restrict__ A1h, const short* __restrict__ A1l,
    const short* __restrict__ A2h, const short* __restrict__ A2l,
    const short* __restrict__ B1hL, const short* __restrict__ B1lL,
    const short* __restrict__ B1hC, const short* __restrict__ B1lC,
    const short* __restrict__ B2hL, const short* __restrict__ B2lL,
    const short* __restrict__ B2hC, const short* __restrict__ B2lC,
    const float* __restrict__ biasL, const float* __restrict__ biasC,
    short* __restrict__ OH, short* __restrict__ OL, float* __restrict__ OF,
    const float* __restrict__ Cold, float* __restrict__ Cnew,
    int Freal, int Fstore, int nx)
{
    __shared__ short sAh[4 * 2048];   // [chunk32 q][row 64][32] per split
    __shared__ short sAl[4 * 2048];
    __shared__ short sBh[4 * 2048];
    __shared__ short sBl[4 * 2048];

    const int flat = blockIdx.x;
    const int qx = (int)gridDim.x >> 3;
    const int wg = (flat & 7) * qx + (flat >> 3);
    const int row0 = (wg / nx) * 64;
    const int c0 = (wg % nx) * 64;
    const bool isC = (row0 >= ROWC0);
    const int t = threadIdx.x;
    const int lane = t & 63;
    const int w = t >> 6;
    const int wr = w >> 1, wc = w & 1;
    const int l15 = lane & 15;

    f32x4 acc[2][2] = {};
    bool first = true;

    const int nph = TWOA ? 2 : 1;
    for (int ph = 0; ph < nph; ++ph) {
        const short* Ah = (TWOA && ph) ? A2h : A1h;
        const short* Al = (TWOA && ph) ? A2l : A1l;
        const short* Bh = (TWOA && ph) ? (isC ? B2hC : B2hL) : (isC ? B1hC : B1hL);
        const short* Bl = (TWOA && ph) ? (isC ? B2lC : B2lL) : (isC ? B1lC : B1lL);

        for (int kc0 = 0; kc0 < KS; kc0 += 128) {
            const int n32 = ((KS - kc0) >> 5) < 4 ? ((KS - kc0) >> 5) : 4;
            if (!first) __syncthreads();   // buffer free (prev chunk consumed)
            first = false;
            const int row = t >> 2, slot = t & 3;
#pragma unroll 4
            for (int q = 0; q < n32; ++q) {
                int gk = kc0 + q * 32 + ((slot ^ ((row >> 1) & 3)) << 3);
                size_t ga = (size_t)(row0 + row) * KS + gk;
                size_t gb = (size_t)(c0 + row) * KS + gk;
                gload16(Ah + ga, &sAh[q * 2048 + t * 8]);
                gload16(Al + ga, &sAl[q * 2048 + t * 8]);
                gload16(Bh + gb, &sBh[q * 2048 + t * 8]);
                gload16(Bl + gb, &sBl[q * 2048 + t * 8]);
            }
            asm volatile("s_waitcnt vmcnt(0)" ::: "memory");
            __syncthreads();
#pragma unroll 4
            for (int q = 0; q < n32; ++q) {
                bf16x8 af[2][2], bf[2][2];
#pragma unroll
                for (int s = 0; s < 2; ++s) {
                    int ar = wr * 32 + s * 16 + l15;
                    int aslot = (lane >> 4) ^ ((ar >> 1) & 3);
                    int ai = q * 2048 + ar * 32 + aslot * 8;
                    af[s][0] = *(const bf16x8*)&sAh[ai];
                    af[s][1] = *(const bf16x8*)&sAl[ai];
                    int br = wc * 32 + s * 16 + l15;
                    int bslot = (lane >> 4) ^ ((br >> 1) & 3);
                    int bi = q * 2048 + br * 32 + bslot * 8;
                    bf[s][0] = *(const bf16x8*)&sBh[bi];
                    bf[s][1] = *(const bf16x8*)&sBl[bi];
                }
#pragma unroll
                for (int s = 0; s < 2; ++s)
#pragma unroll
                    for (int u = 0; u < 2; ++u) {
                        acc[s][u] = __builtin_amdgcn_mfma_f32_16x16x32_bf16(af[s][0], bf[u][0], acc[s][u], 0, 0, 0);
                        acc[s][u] = __builtin_amdgcn_mfma_f32_16x16x32_bf16(af[s][0], bf[u][1], acc[s][u], 0, 0, 0);
                        acc[s][u] = __builtin_amdgcn_mfma_f32_16x16x32_bf16(af[s][1], bf[u][0], acc[s][u], 0, 0, 0);
                    }
            }
        }
    }

    if (OUTM != 3) {
        // C/D frag layout: col = lane&15, row = (lane>>4)*4 + reg (m89)
#pragma unroll
        for (int u = 0; u < 2; ++u) {
            int col = c0 + wc * 32 + u * 16 + l15;
            if (col >= Fstore) continue;
            float bv = (col < Freal) ? (isC ? biasC[col] : biasL[col]) : 0.f;
#pragma unroll
            for (int s = 0; s < 2; ++s)
#pragma unroll
                for (int j = 0; j < 4; ++j) {
                    int rowo = row0 + wr * 32 + s * 16 + (lane >> 4) * 4 + j;
                    float v = acc[s][u][j] + bv;
                    if (RELU) v = fmaxf(v, 0.f);
                    size_t oi = (size_t)rowo * Fstore + col;
                    if (OUTM == 1) {
                        short h = f2bf(v);
                        OH[oi] = h;
                        OL[oi] = f2bf(v - bf2f(h));
                    } else {
                        ((_Float16*)OF)[oi] = (_Float16)v;
                    }
                }
        }
    } else {
        // Fused LSTM epilogue (R5-R14 verified). colp = permuted gate col 4j+g.
        const int ql = lane & 3;
#pragma unroll
        for (int u = 0; u < 2; ++u) {
            int colp = c0 + wc * 32 + u * 16 + l15;
            int wrr = (colp & 3) * 128 + (colp >> 2);
            float bv = isC ? biasC[wrr] : biasL[wrr];
            int j = colp >> 2;
#pragma unroll
            for (int s = 0; s < 2; ++s) {
                float ii = 0.f, ff = 0.f, gg = 0.f, oo = 0.f;
#pragma unroll
                for (int r2 = 0; r2 < 4; ++r2) {
                    float v0 = acc[s][u][r2] + bv;
                    float x1 = __shfl_xor(v0, 1);
                    float x2 = __shfl_xor(v0, 2);
                    float x3 = __shfl_xor(v0, 3);
                    float iv = (ql == 0) ? v0 : (ql == 1) ? x1 : (ql == 2) ? x2 : x3;
                    float fv = (ql == 0) ? x1 : (ql == 1) ? v0 : (ql == 2) ? x3 : x2;
                    float gv = (ql == 0) ? x2 : (ql == 1) ? x3 : (ql == 2) ? v0 : x1;
                    float ov = (ql == 0) ? x3 : (ql == 1) ? x2 : (ql == 2) ? x1 : v0;
                    if (ql == r2) { ii = iv; ff = fv; gg = gv; oo = ov; }
                }
                int rowo = row0 + wr * 32 + s * 16 + (lane >> 4) * 4 + ql;
                size_t ci = (size_t)rowo * 128 + j;
                float c2 = sigf(ff) * Cold[ci] + sigf(ii) * tanhf(gg);
                float h2 = sigf(oo) * tanhf(c2);
                Cnew[ci] = c2;
                short h = f2bf(h2);
                OH[ci] = h;
                OL[ci] = f2bf(h2 - bf2f(h));
            }
        }
    }
}

// ---------------------------------------------------------------------------
// SpMM gather (R12-verified): 4-edge-parallel, dwordx4, shfl fold.
// ---------------------------------------------------------------------------
__global__ __launch_bounds__(256) void spmm_kernel(
    const int* __restrict__ Lp, const int* __restrict__ Li,
    const int* __restrict__ Tp, const int* __restrict__ Ti,
    const _Float16* __restrict__ X, short* __restrict__ mh, short* __restrict__ ml)
{
    const int r = blockIdx.x * 4 + (threadIdx.x >> 6);
    const int lane = threadIdx.x & 63;
    const int eg = lane >> 4;
    const int cl = lane & 15;
    if (r >= NRREAL) return;
    const int cp = cl * 8;

    int b, e, base;
    const int* idx;
    if (r < NL) { b = Lp[r]; e = Lp[r + 1]; idx = Li; base = ROWC0; }
    else if (r >= ROWC0) { int c = r - ROWC0; b = Tp[c]; e = Tp[c + 1]; idx = Ti; base = 0; }
    else return;

    float s0 = 0.f, s1 = 0.f, s2 = 0.f, s3 = 0.f, s4 = 0.f, s5 = 0.f, s6 = 0.f, s7 = 0.f;
    int i = b + eg;
    bool has = i < e;
    uint4 v = make_uint4(0, 0, 0, 0);
    if (has) v = *(const uint4*)&X[(size_t)(base + idx[i]) * EMB + cp];
    while (has) {
        int in_ = i + 4;
        bool hn = in_ < e;
        uint4 vn = v;
        if (hn) vn = *(const uint4*)&X[(size_t)(base + idx[in_]) * EMB + cp];
        float2 f0 = h2f2(v.x), f1 = h2f2(v.y), f2 = h2f2(v.z), f3 = h2f2(v.w);
        s0 += f0.x; s1 += f0.y; s2 += f1.x; s3 += f1.y;
        s4 += f2.x; s5 += f2.y; s6 += f3.x; s7 += f3.y;
        v = vn; i = in_; has = hn;
    }
    s0 += __shfl_xor(s0, 16); s0 += __shfl_xor(s0, 32);
    s1 += __shfl_xor(s1, 16); s1 += __shfl_xor(s1, 32);
    s2 += __shfl_xor(s2, 16); s2 += __shfl_xor(s2, 32);
    s3 += __shfl_xor(s3, 16); s3 += __shfl_xor(s3, 32);
    s4 += __shfl_xor(s4, 16); s4 += __shfl_xor(s4, 32);
    s5 += __shfl_xor(s5, 16); s5 += __shfl_xor(s5, 32);
    s6 += __shfl_xor(s6, 16); s6 += __shfl_xor(s6, 32);
    s7 += __shfl_xor(s7, 16); s7 += __shfl_xor(s7, 32);

    if (eg == 0) {
        float sv[8] = { s0, s1, s2, s3, s4, s5, s6, s7 };
        unsigned hp[4], lp[4];
#pragma unroll
        for (int j = 0; j < 4; ++j) {
            short ha = f2bf(sv[2 * j]), hb = f2bf(sv[2 * j + 1]);
            hp[j] = (unsigned)(unsigned short)ha | ((unsigned)(unsigned short)hb << 16);
            short la = f2bf(sv[2 * j] - bf2f(ha)), lb = f2bf(sv[2 * j + 1] - bf2f(hb));
            lp[j] = (unsigned)(unsigned short)la | ((unsigned)(unsigned short)lb << 16);
        }
        size_t oi = (size_t)r * EMB + cp;
        *(uint4*)&mh[oi] = make_uint4(hp[0], hp[1], hp[2], hp[3]);
        *(uint4*)&ml[oi] = make_uint4(lp[0], lp[1], lp[2], lp[3]);
    }
}

__global__ __launch_bounds__(256) void init_states(
    const float* __restrict__ Li, const float* __restrict__ Ci,
    short* __restrict__ Hh, short* __restrict__ Hl, float* __restrict__ C,
    short* __restrict__ msgsH, short* __restrict__ msgsL, float* __restrict__ accum)
{
    size_t idx = (size_t)blockIdx.x * 256 + threadIdx.x;
    if (idx >= (size_t)NRP * EMB) return;
    int r = (int)(idx >> 7);
    int e = (int)(idx & 127);
    float h = 0.f;
    if (r < NL) h = Li[e];
    else if (r >= ROWC0 && r < NRREAL) h = Ci[e];
    short hh = f2bf(h);
    Hh[idx] = hh;
    Hl[idx] = f2bf(h - bf2f(hh));
    C[idx] = 0.f;
    if (r >= NRREAL || (r >= NL && r < ROWC0)) { msgsH[idx] = 0; msgsL[idx] = 0; }
    if (idx == 0) accum[0] = 0.f;
}

// ---------------------------------------------------------------------------
// Merged weight split (1 dispatch; verified). perm = LSTM gate permutation.
// ---------------------------------------------------------------------------
struct SplitJobs {
    const float* src[12];
    short* dh[12]; short* dl[12];
    int rows[12], cols[12], prows[12], pcols[12], perm[12];
};

__global__ __launch_bounds__(256) void split_all(SplitJobs J)
{
    int j = blockIdx.y;
    int i = blockIdx.x * 256 + threadIdx.x;
    int pr = J.prows[j], pc = J.pcols[j];
    if (i >= pr * pc) return;
    int pp = i / pc, c = i - pp * pc;
    int r = J.perm[j] ? (((pp & 3) << 7) | (pp >> 2)) : pp;
    float v = (r < J.rows[j] && c < J.cols[j]) ? J.src[j][(size_t)r * J.cols[j] + c] : 0.f;
    short h = f2bf(v);
    J.dh[j][i] = h;
    J.dl[j][i] = f2bf(v - bf2f(h));
}

// ---------------------------------------------------------------------------
// CSR build (R15: all M passes float4-vectorized; fill_L via 4-ballot rank)
// ---------------------------------------------------------------------------
__global__ __launch_bounds__(256) void count_rows_L(const float* __restrict__ M, int* __restrict__ cnt)
{
    int l = blockIdx.x, t = threadIdx.x;
    int n = 0;
    for (int c4 = t; c4 < NC / 4; c4 += 256) {
        float4 v = *(const float4*)&M[(size_t)l * NC + c4 * 4];
        n += (v.x != 0.f) + (v.y != 0.f) + (v.z != 0.f) + (v.w != 0.f);
    }
#pragma unroll
    for (int off = 32; off > 0; off >>= 1) n += __shfl_down(n, off);
    __shared__ int wsum[4];
    if ((t & 63) == 0) wsum[t >> 6] = n;
    __syncthreads();
    if (t == 0) cnt[l] = wsum[0] + wsum[1] + wsum[2] + wsum[3];
}

__global__ __launch_bounds__(256) void count_T(const float* __restrict__ M, int* __restrict__ cnt2d)
{
    int s = blockIdx.y;
    int c4 = blockIdx.x * 256 + threadIdx.x;
    if (c4 >= NC / 4) return;
    int n0 = 0, n1 = 0, n2 = 0, n3 = 0;
    int l0 = s * LCHUNK, l1 = l0 + LCHUNK;
    for (int l = l0; l < l1; ++l) {
        float4 v = *(const float4*)&M[(size_t)l * NC + c4 * 4];
        n0 += v.x != 0.f; n1 += v.y != 0.f; n2 += v.z != 0.f; n3 += v.w != 0.f;
    }
    size_t o = (size_t)s * NC + c4 * 4;
    cnt2d[o] = n0; cnt2d[o + 1] = n1; cnt2d[o + 2] = n2; cnt2d[o + 3] = n3;
}

__device__ void scan_excl_dev(const int* __restrict__ in, int* __restrict__ out, int n)
{
    const int t = threadIdx.x;
    const int per = (n + 255) >> 8;
    __shared__ int part[256];
    int s = 0;
    const int start = t * per;
    for (int i = 0; i < per; ++i) { int idx = start + i; if (idx < n) s += in[idx]; }
    part[t] = s;
    __syncthreads();
    for (int off = 1; off < 256; off <<= 1) {
        int v = (t >= off) ? part[t - off] : 0;
        __syncthreads();
        part[t] += v;
        __syncthreads();
    }
    int run = (t == 0) ? 0 : part[t - 1];
    for (int i = 0; i < per; ++i) {
        int idx = start + i;
        if (idx < n) { out[idx] = run; run += in[idx]; }
    }
    if (t == 255) out[n] = part[255];
}

__global__ __launch_bounds__(256) void scan_both(const int* __restrict__ cntT, int* __restrict__ Tp,
                                                 const int* __restrict__ cntL, int* __restrict__ Lp)
{
    if (blockIdx.x == 0) scan_excl_dev(cntT, Tp, NC);
    else scan_excl_dev(cntL, Lp, NL);
}

// fill_L (R15): float4 loads + 4 ballots per 1024-col chunk; rank preserves
// ascending column order exactly (lanes-below popcount + intra-lane k order).
__global__ __launch_bounds__(256) void fill_L(const float* __restrict__ M,
                                              const int* __restrict__ Lp, int* __restrict__ Lidx)
{
    int l = blockIdx.x, t = threadIdx.x, lane = t & 63, wid = t >> 6;
    __shared__ int wcnt[4];
    __shared__ int base;
    if (t == 0) base = Lp[l];
    __syncthreads();
    for (int c0 = 0; c0 < NC; c0 += 1024) {
        int c = c0 + t * 4;
        float4 v = make_float4(0.f, 0.f, 0.f, 0.f);
        if (c + 3 < NC) v = *(const float4*)&M[(size_t)l * NC + c];
        bool p0 = v.x != 0.f, p1 = v.y != 0.f, p2 = v.z != 0.f, p3 = v.w != 0.f;
        unsigned long long m0 = __ballot(p0), m1 = __ballot(p1);
        unsigned long long m2 = __ballot(p2), m3 = __ballot(p3);
        int cnt = __popcll(m0) + __popcll(m1) + __popcll(m2) + __popcll(m3);
        if (lane == 0) wcnt[wid] = cnt;
        __syncthreads();
        int off = base;
        for (int w = 0; w < wid; ++w) off += wcnt[w];
        unsigned long long below = (1ull << lane) - 1ull;
        int rank = __popcll(m0 & below) + __popcll(m1 & below)
                 + __popcll(m2 & below) + __popcll(m3 & below);
        if (p0) Lidx[off + rank] = c;     rank += p0;
        if (p1) Lidx[off + rank] = c + 1; rank += p1;
        if (p2) Lidx[off + rank] = c + 2; rank += p2;
        if (p3) Lidx[off + rank] = c + 3;
        __syncthreads();
        if (t == 0) base += wcnt[0] + wcnt[1] + wcnt[2] + wcnt[3];
        __syncthreads();
    }
}

__global__ __launch_bounds__(256) void colscan_T(const int* __restrict__ cnt2d,
                                                 int* __restrict__ cum2d, int* __restrict__ cntT)
{
    int c = blockIdx.x * 256 + threadIdx.x;
    if (c >= NC) return;
    int run = 0;
    for (int s = 0; s < NCHUNK; ++s) {
        cum2d[(size_t)s * NC + c] = run;
        run += cnt2d[(size_t)s * NC + c];
    }
    cntT[c] = run;
}

__global__ __launch_bounds__(256) void fill_T(const float* __restrict__ M,
                                              const int* __restrict__ Tp, const int* __restrict__ cum2d,
                                              int* __restrict__ Tidx)
{
    int s = blockIdx.y;
    int c4 = blockIdx.x * 256 + threadIdx.x;
    if (c4 >= NC / 4) return;
    int c = c4 * 4;
    int p0 = Tp[c] + cum2d[(size_t)s * NC + c];
    int p1 = Tp[c + 1] + cum2d[(size_t)s * NC + c + 1];
    int p2 = Tp[c + 2] + cum2d[(size_t)s * NC + c + 2];
    int p3 = Tp[c + 3] + cum2d[(size_t)s * NC + c + 3];
    int l0 = s * LCHUNK, l1 = l0 + LCHUNK;
    for (int l = l0; l < l1; ++l) {
        float4 v = *(const float4*)&M[(size_t)l * NC + c];
        if (v.x != 0.f) Tidx[p0++] = l;
        if (v.y != 0.f) Tidx[p1++] = l;
        if (v.z != 0.f) Tidx[p2++] = l;
        if (v.w != 0.f) Tidx[p3++] = l;
    }
}

// ---------------------------------------------------------------------------
// Vote epilogue
// ---------------------------------------------------------------------------
__global__ __launch_bounds__(256) void vote_reduce(
    const short* __restrict__ H2h, const short* __restrict__ H2l,
    const float* __restrict__ W3, const float* __restrict__ b3, float* __restrict__ accum)
{
    int wid = threadIdx.x >> 6, lane = threadIdx.x & 63;
    int r = blockIdx.x * 4 + wid;
    float s = 0.f;
    if (r < NL) {
        const short* xh = &H2h[(size_t)r * 224];
        const short* xl = &H2l[(size_t)r * 224];
        for (int k = lane; k < 200; k += 64) s += (bf2f(xh[k]) + bf2f(xl[k])) * W3[k];
    }
#pragma unroll
    for (int off = 32; off > 0; off >>= 1) s += __shfl_down(s, off);
    if (lane == 0 && r < NL) {
        float v = 1.f / (1.f + expf(-(s + b3[0])));
        atomicAdd(accum, v);
    }
}

__global__ void finalize_logit(const float* __restrict__ accum, float* __restrict__ out)
{
    float avg = accum[0] / (float)NL;
    out[0] = logf(avg / (1.f - avg));
}

// ---------------------------------------------------------------------------
// Host launcher (R14 structure)
// ---------------------------------------------------------------------------
extern "C" void kernel_launch(void* const* d_in, const int* in_sizes, int n_in,
                              void* d_out, int out_size, void* d_ws, size_t ws_size,
                              hipStream_t stream)
{
    const float* M      = (const float*)d_in[0];
    const float* L_init = (const float*)d_in[1];
    const float* C_init = (const float*)d_in[2];
    const float* LC_W1 = (const float*)d_in[3];  const float* LC_b1 = (const float*)d_in[4];
    const float* LC_W2 = (const float*)d_in[5];  const float* LC_b2 = (const float*)d_in[6];
    const float* LC_W3 = (const float*)d_in[7];  const float* LC_b3 = (const float*)d_in[8];
    const float* CL_W1 = (const float*)d_in[9];  const float* CL_b1 = (const float*)d_in[10];
    const float* CL_W2 = (const float*)d_in[11]; const float* CL_b2 = (const float*)d_in[12];
    const float* CL_W3 = (const float*)d_in[13]; const float* CL_b3 = (const float*)d_in[14];
    const float* L_Wih = (const float*)d_in[15]; const float* L_Whh = (const float*)d_in[16];
    const float* L_b   = (const float*)d_in[17];
    const float* C_Wih = (const float*)d_in[18]; const float* C_Whh = (const float*)d_in[19];
    const float* C_b   = (const float*)d_in[20];
    const float* V_W1 = (const float*)d_in[21]; const float* V_b1 = (const float*)d_in[22];
    const float* V_W2 = (const float*)d_in[23]; const float* V_b2 = (const float*)d_in[24];
    const float* V_W3 = (const float*)d_in[25]; const float* V_b3 = (const float*)d_in[26];
    float* out = (float*)d_out;

    char* ws = (char*)d_ws;
    size_t off = 0;
    auto alloc = [&](size_t bytes) -> void* {
        void* pt = ws + off;
        off += (bytes + 255) & ~(size_t)255;
        return pt;
    };
    const size_t NE = (size_t)NRP * EMB;
    short* HAh = (short*)alloc(NE * 2); short* HAl = (short*)alloc(NE * 2);
    short* HBh = (short*)alloc(NE * 2); short* HBl = (short*)alloc(NE * 2);
    float* CA = (float*)alloc(NE * 4);  float* CB = (float*)alloc(NE * 4);
    short* msgsH = (short*)alloc(NE * 2); short* msgsL = (short*)alloc(NE * 2);
    _Float16* X = (_Float16*)alloc(NE * 2);
    short* H1h = (short*)alloc((size_t)NRP * 416 * 2); short* H1l = (short*)alloc((size_t)NRP * 416 * 2);
    short* H2h = (short*)alloc((size_t)NRP * 224 * 2); short* H2l = (short*)alloc((size_t)NRP * 224 * 2);
    float* accum = (float*)alloc(256);
    short* W1hL = (short*)alloc(512 * 128 * 2); short* W1lL = (short*)alloc(512 * 128 * 2);
    short* W1hC = (short*)alloc(512 * 128 * 2); short* W1lC = (short*)alloc(512 * 128 * 2);
    short* W2hL = (short*)alloc(256 * 416 * 2); short* W2lL = (short*)alloc(256 * 416 * 2);
    short* W2hC = (short*)alloc(256 * 416 * 2); short* W2lC = (short*)alloc(256 * 416 * 2);
    short* W3hL = (short*)alloc(128 * 224 * 2); short* W3lL = (short*)alloc(128 * 224 * 2);
    short* W3hC = (short*)alloc(128 * 224 * 2); short* W3lC = (short*)alloc(128 * 224 * 2);
    short* WihhL = (short*)alloc(512 * 128 * 2); short* WihlL = (short*)alloc(512 * 128 * 2);
    short* WhhhL = (short*)alloc(512 * 128 * 2); short* WhhlL = (short*)alloc(512 * 128 * 2);
    short* WihhC = (short*)alloc(512 * 128 * 2); short* WihlC = (short*)alloc(512 * 128 * 2);
    short* WhhhC = (short*)alloc(512 * 128 * 2); short* WhhlC = (short*)alloc(512 * 128 * 2);
    short* V1h = (short*)alloc(512 * 128 * 2); short* V1l = (short*)alloc(512 * 128 * 2);
    short* V2h = (short*)alloc(256 * 416 * 2); short* V2l = (short*)alloc(256 * 416 * 2);
    int* Lp   = (int*)alloc(4104 * 4);
    int* Tp   = (int*)alloc(8104 * 4);
    int* Lidx = (int*)alloc(1000000 * 4);
    int* Tidx = (int*)alloc(1000000 * 4);
    int* cnt2d = (int*)alloc((size_t)NCHUNK * NC * 4);
    int* cum2d = (int*)alloc((size_t)NCHUNK * NC * 4);
    int* cntL = (int*)alloc(4096 * 4);
    int* cntT = (int*)alloc(8192 * 4);
    (void)ws_size; (void)in_sizes; (void)n_in; (void)out_size;

    // --- CSR build (all passes vectorized; scans merged) ---
    count_rows_L<<<NL, 256, 0, stream>>>(M, cntL);
    {
        dim3 g((NC / 4 + 255) / 256, NCHUNK);
        count_T<<<g, 256, 0, stream>>>(M, cnt2d);
        colscan_T<<<(NC + 255) / 256, 256, 0, stream>>>(cnt2d, cum2d, cntT);
        scan_both<<<2, 256, 0, stream>>>(cntT, Tp, cntL, Lp);
        fill_L<<<NL, 256, 0, stream>>>(M, Lp, Lidx);
        fill_T<<<g, 256, 0, stream>>>(M, Tp, cum2d, Tidx);
    }

    // --- merged weight split (1 dispatch) ---
    SplitJobs Jb{};
    auto setj = [&](int j, const float* s, short* dh, short* dl, int r, int c, int pr, int pc, int pm) {
        Jb.src[j] = s; Jb.dh[j] = dh; Jb.dl[j] = dl;
        Jb.rows[j] = r; Jb.cols[j] = c; Jb.prows[j] = pr; Jb.pcols[j] = pc; Jb.perm[j] = pm;
    };
    setj(0, LC_W1, W1hL, W1lL, 400, 128, 512, 128, 0);
    setj(1, CL_W1, W1hC, W1lC, 400, 128, 512, 128, 0);
    setj(2, LC_W2, W2hL, W2lL, 200, 400, 256, 416, 0);
    setj(3, CL_W2, W2hC, W2lC, 200, 400, 256, 416, 0);
    setj(4, LC_W3, W3hL, W3lL, 128, 200, 128, 224, 0);
    setj(5, CL_W3, W3hC, W3lC, 128, 200, 128, 224, 0);
    setj(6, L_Wih, WihhL, WihlL, 512, 128, 512, 128, 1);
    setj(7, L_Whh, WhhhL, WhhlL, 512, 128, 512, 128, 1);
    setj(8, C_Wih, WihhC, WihlC, 512, 128, 512, 128, 1);
    setj(9, C_Whh, WhhhC, WhhlC, 512, 128, 512, 128, 1);
    setj(10, V_W1, V1h, V1l, 400, 128, 512, 128, 0);
    setj(11, V_W2, V2h, V2l, 200, 400, 256, 416, 0);
    {
        dim3 g((106496 + 255) / 256, 12);
        split_all<<<g, 256, 0, stream>>>(Jb);
    }

    const int nelem_blocks = (int)((NE + 255) / 256);
    init_states<<<nelem_blocks, 256, 0, stream>>>(L_init, C_init, HAh, HAl, CA, msgsH, msgsL, accum);

    // --- 30 message-passing steps (5 kernels each; 1-D swizzled grids) ---
    short *Hch = HAh, *Hcl = HAl, *Hnh = HBh, *Hnl = HBl;
    float *Ccur = CA, *Cnxt = CB;
    for (int step = 0; step < TSTEPS; ++step) {
        gemm64<128, 1, false, true><<<7 * 192, 256, 0, stream>>>(
            Hch, Hcl, nullptr, nullptr,
            W1hL, W1lL, W1hC, W1lC, nullptr, nullptr, nullptr, nullptr,
            LC_b1, CL_b1, H1h, H1l, nullptr, nullptr, nullptr, 400, 416, 7);
        gemm64<416, 1, false, true><<<4 * 192, 256, 0, stream>>>(
            H1h, H1l, nullptr, nullptr,
            W2hL, W2lL, W2hC, W2lC, nullptr, nullptr, nullptr, nullptr,
            LC_b2, CL_b2, H2h, H2l, nullptr, nullptr, nullptr, 200, 224, 4);
        gemm64<224, 4, false, false><<<2 * 192, 256, 0, stream>>>(
            H2h, H2l, nullptr, nullptr,
            W3hL, W3lL, W3hC, W3lC, nullptr, nullptr, nullptr, nullptr,
            LC_b3, CL_b3, nullptr, nullptr, (float*)X, nullptr, nullptr, 128, 128, 2);
        spmm_kernel<<<(NRREAL + 3) / 4, 256, 0, stream>>>(Lp, Lidx, Tp, Tidx, X, msgsH, msgsL);
        gemm64<128, 3, true, false><<<8 * 192, 256, 0, stream>>>(
            msgsH, msgsL, Hch, Hcl,
            WihhL, WihlL, WihhC, WihlC, WhhhL, WhhlL, WhhhC, WhhlC,
            L_b, C_b, Hnh, Hnl, nullptr, Ccur, Cnxt, 512, 512, 8);
        short* th = Hch; Hch = Hnh; Hnh = th;
        short* tl = Hcl; Hcl = Hnl; Hnl = tl;
        float* tc = Ccur; Ccur = Cnxt; Cnxt = tc;
    }

    // --- vote MLP + logit (lit rows only: 64 row panels of 64) ---
    gemm64<128, 1, false, true><<<7 * 64, 256, 0, stream>>>(
        Hch, Hcl, nullptr, nullptr,
        V1h, V1l, V1h, V1l, nullptr, nullptr, nullptr, nullptr,
        V_b1, V_b1, H1h, H1l, nullptr, nullptr, nullptr, 400, 416, 7);
    gemm64<416, 1, false, true><<<4 * 64, 256, 0, stream>>>(
        H1h, H1l, nullptr, nullptr,
        V2h, V2l, V2h, V2l, nullptr, nullptr, nullptr, nullptr,
        V_b2, V_b2, H2h, H2l, nullptr, nullptr, nullptr, 200, 224, 4);
    vote_reduce<<<(NL + 3) / 4, 256, 0, stream>>>(H2h, H2l, V_W3, V_b3, accum);
    finalize_logit<<<1, 1, 0, stream>>>(accum, out);
}